// Round 4
// baseline (1316.136 us; speedup 1.0000x reference)
//
#include <hip/hip_runtime.h>

#define N_TOK 8192
#define DIM   2048
#define FFN   1408
#define NEXP  8

// ---------- ws layout (bytes) ----------
#define X_OFF   0ull                          // x bf16 [N][D]
#define WG_OFF  33554432ull                   // wg_t bf16 [E][F][D]
#define WU_OFF  79691776ull
#define WD_OFF  125829120ull                  // wd_t bf16 [E][D][F]
#define H_OFF   171966464ull                  // h bf16 [2N][F]
#define LPK_OFF 218103808ull
#define LW_OFF  218169344ull
#define TI_OFF  218234880ull
#define TW_OFF  218267648ull
#define ST_OFF  218300416ull

typedef __bf16 bf16x8 __attribute__((ext_vector_type(8)));
typedef float  f32x4  __attribute__((ext_vector_type(4)));
typedef int    int4v  __attribute__((ext_vector_type(4)));
typedef __attribute__((address_space(1))) void as1_void;
typedef __attribute__((address_space(3))) void as3_void;

__device__ __forceinline__ void gload16(const void* g, void* l) {
  __builtin_amdgcn_global_load_lds((as1_void*)g, (as3_void*)l, 16, 0, 0);
}

__device__ __forceinline__ ushort f2bf(float f) {
  unsigned u = __builtin_bit_cast(unsigned, f);
  u += 0x7FFFu + ((u >> 16) & 1u);
  return (ushort)(u >> 16);
}

__device__ __forceinline__ int4v dsread(int addr) {
  int4v d;
  asm volatile("ds_read_b128 %0, %1" : "=v"(d) : "v"(addr));
  return d;
}

#define WAITL() do { asm volatile("s_waitcnt lgkmcnt(0)" ::: "memory"); \
                     __builtin_amdgcn_sched_barrier(0); } while (0)
#define BAR()   __builtin_amdgcn_s_barrier()
#define MFMA16(a, b, c) __builtin_amdgcn_mfma_f32_16x16x32_bf16(a, b, c, 0, 0, 0)
#define BC(x) __builtin_bit_cast(bf16x8, x)

// LDS unit layout: [row-pair q][8 pos of 16B], pos p = (((row&1)<<2)|slot) ^ (q&7).
__device__ __forceinline__ int swz(int row, int s) {
  int q = row >> 1;
  int p = (((row & 1) << 2) | s) ^ (q & 7);
  return q * 128 + p * 16;
}

// ---------------- router ----------------
__global__ __launch_bounds__(256) void router_kernel(
    const float* __restrict__ x, const float* __restrict__ rw,
    ushort* __restrict__ xb, int* __restrict__ topi, float* __restrict__ topw,
    int* __restrict__ cnt, unsigned long long* __restrict__ psum)
{
  int tid = threadIdx.x, lane = tid & 63, wv = tid >> 6;
  __shared__ float sP[4][8];
  __shared__ int   sC[4][8];
  float pacc[8]; int cacc[8];
  #pragma unroll
  for (int e = 0; e < 8; ++e) { pacc[e] = 0.f; cacc[e] = 0; }

  #pragma unroll 1
  for (int it = 0; it < 4; ++it) {
    int t = blockIdx.x * 16 + wv * 4 + it;
    const float4* xr = (const float4*)(x + (size_t)t * DIM);
    float acc[8];
    #pragma unroll
    for (int e = 0; e < 8; ++e) acc[e] = 0.f;
    #pragma unroll 1
    for (int i = 0; i < 8; ++i) {
      int j = i * 64 + lane;
      float4 v = xr[j];
      ushort4 o; o.x = f2bf(v.x); o.y = f2bf(v.y); o.z = f2bf(v.z); o.w = f2bf(v.w);
      *(ushort4*)(xb + (size_t)t * DIM + (size_t)j * 4) = o;
      const float* rr = rw + (size_t)j * 32;
      #pragma unroll
      for (int c = 0; c < 4; ++c) {
        float xv = (&v.x)[c];
        const float4* r4 = (const float4*)(rr + c * 8);
        float4 q0 = r4[0], q1 = r4[1];
        acc[0] += xv * q0.x; acc[1] += xv * q0.y; acc[2] += xv * q0.z; acc[3] += xv * q0.w;
        acc[4] += xv * q1.x; acc[5] += xv * q1.y; acc[6] += xv * q1.z; acc[7] += xv * q1.w;
      }
    }
    #pragma unroll
    for (int off = 32; off; off >>= 1) {
      #pragma unroll
      for (int e = 0; e < 8; ++e) acc[e] += __shfl_xor(acc[e], off);
    }
    float m = acc[0];
    #pragma unroll
    for (int e = 1; e < 8; ++e) m = fmaxf(m, acc[e]);
    float p[8], s = 0.f;
    #pragma unroll
    for (int e = 0; e < 8; ++e) { p[e] = __expf(acc[e] - m); s += p[e]; }
    float inv = 1.f / s;
    int i1 = 0; float p1 = p[0];
    #pragma unroll
    for (int e = 1; e < 8; ++e) if (p[e] > p1) { p1 = p[e]; i1 = e; }
    int i2 = -1; float p2 = -1.f;
    #pragma unroll
    for (int e = 0; e < 8; ++e) if (e != i1 && p[e] > p2) { p2 = p[e]; i2 = e; }
    float w1 = p1 / (p1 + p2);
    if (lane == 0) {
      topi[t] = i1 | (i2 << 8);
      topw[t] = w1;
      #pragma unroll
      for (int e = 0; e < 8; ++e) pacc[e] += p[e] * inv;
      cacc[i1]++; cacc[i2]++;
    }
  }
  if (lane == 0) {
    #pragma unroll
    for (int e = 0; e < 8; ++e) { sP[wv][e] = pacc[e]; sC[wv][e] = cacc[e]; }
  }
  __syncthreads();
  if (tid < 8) {
    float ps = sP[0][tid] + sP[1][tid] + sP[2][tid] + sP[3][tid];
    int   cs = sC[0][tid] + sC[1][tid] + sC[2][tid] + sC[3][tid];
    atomicAdd(&cnt[tid], cs);
    atomicAdd(&psum[tid], (unsigned long long)((double)ps * 1099511627776.0));
  }
}

// ---------------- scan + aux ----------------
__global__ void scan_aux_kernel(int* __restrict__ stats,
                                const unsigned long long* __restrict__ psum,
                                float* __restrict__ aux_out)
{
  if (threadIdx.x == 0 && blockIdx.x == 0) {
    int b = 0;
    for (int e = 0; e < 8; ++e) { stats[16 + e] = b; stats[8 + e] = b; b += stats[e]; }
    double s = 0.0;
    for (int e = 0; e < 8; ++e)
      s += (double)stats[e] * ((double)psum[e] * (1.0 / 1099511627776.0));
    aux_out[0] = (float)(4.0 * s / ((double)N_TOK * (double)N_TOK));
  }
}

// ---------------- placement ----------------
__global__ __launch_bounds__(256) void place_kernel(
    const int* __restrict__ topi, const float* __restrict__ topw,
    int* __restrict__ stats, int* __restrict__ lpk, float* __restrict__ lw)
{
  int t = blockIdx.x * 256 + threadIdx.x;
  if (t >= N_TOK) return;
  int pk = topi[t];
  int e1 = pk & 0xff, e2 = (pk >> 8) & 0xff;
  float w1 = topw[t];
  int p1 = atomicAdd(&stats[8 + e1], 1);
  lpk[p1] = (t << 1); lw[p1] = w1;
  int p2 = atomicAdd(&stats[8 + e2], 1);
  lpk[p2] = (t << 1) | 1; lw[p2] = 1.f - w1;
}

// ---------------- transpose-convert f32 -> bf16 ----------------
__global__ __launch_bounds__(256) void conv_t_kernel(
    const float* __restrict__ src, ushort* __restrict__ dst, int R, int C)
{
  __shared__ float t[32][33];
  int e = blockIdx.z;
  int rb = blockIdx.y << 5, cb = blockIdx.x << 5;
  int x = threadIdx.x & 31, y = threadIdx.x >> 5;
  const float* s = src + ((size_t)e * R + rb) * C + cb;
  #pragma unroll
  for (int i = 0; i < 4; ++i) t[y + i * 8][x] = s[(size_t)(y + i * 8) * C + x];
  __syncthreads();
  ushort* d = dst + ((size_t)e * C + cb) * R + rb;
  #pragma unroll
  for (int i = 0; i < 4; ++i) { int c = y + i * 8; d[(size_t)c * R + x] = f2bf(t[x][c]); }
}

// =====================================================================
// Shared GEMM machinery: BM=BN=256, BK=32 chunk, ring of 4 LDS slots
// (32KB each: A 16KB + B 16KB), prefetch distance 3, 8 waves (2M x 4N),
// per-wave 128x64 output, vmcnt(10) steady / 8/4/0 tail, 2 barriers/chunk.
// ORDER: vmcnt -> s_barrier -> ds_read (cross-wave staging visibility!).
// =====================================================================

#define STAGE_A(J) do { size_t kb_ = (size_t)(J) * 64; int d_ = ((J) & 3) * 32768 + wv * 2048; \
  gload16(aS1 + kb_, sm + d_); gload16(aS2 + kb_, sm + d_ + 1024); } while (0)
#define STAGE_B(J) do { size_t kb_ = (size_t)(J) * 64; int d_ = ((J) & 3) * 32768 + 16384 + wv * 2048; \
  gload16(bS1 + kb_, sm + d_); gload16(bS2 + kb_, sm + d_ + 1024); } while (0)

#define VMW(J, NCH) do { \
  if ((J) < (NCH) - 3)       asm volatile("s_waitcnt vmcnt(10)" ::: "memory"); \
  else if ((J) == (NCH) - 3) asm volatile("s_waitcnt vmcnt(8)"  ::: "memory"); \
  else if ((J) == (NCH) - 2) asm volatile("s_waitcnt vmcnt(4)"  ::: "memory"); \
  else                       asm volatile("s_waitcnt vmcnt(0)"  ::: "memory"); \
} while (0)

#define KLOOP(NCH) \
  for (int j = 0; j < (NCH); ++j) { \
    int sb = (j & 3) * 32768; \
    /* phase 1: m-quad 0 */ \
    if (j + 3 < (NCH)) STAGE_A(j + 3); \
    VMW(j, (NCH)); \
    BAR(); \
    int4v vb[4], va[4]; \
    _Pragma("unroll") for (int n = 0; n < 4; ++n) vb[n] = dsread(sb + adB[n]); \
    _Pragma("unroll") for (int m = 0; m < 4; ++m) va[m] = dsread(sb + adA0[m]); \
    WAITL(); \
    __builtin_amdgcn_s_setprio(1); \
    _Pragma("unroll") for (int m = 0; m < 4; ++m) \
      _Pragma("unroll") for (int n = 0; n < 4; ++n) \
        acc[m][n] = MFMA16(BC(va[m]), BC(vb[n]), acc[m][n]); \
    __builtin_amdgcn_s_setprio(0); \
    /* phase 2: m-quad 1 */ \
    if (j + 3 < (NCH)) STAGE_B(j + 3); \
    _Pragma("unroll") for (int m = 0; m < 4; ++m) va[m] = dsread(sb + adA1[m]); \
    WAITL(); \
    __builtin_amdgcn_s_setprio(1); \
    _Pragma("unroll") for (int m = 0; m < 4; ++m) \
      _Pragma("unroll") for (int n = 0; n < 4; ++n) \
        acc[4 + m][n] = MFMA16(BC(va[m]), BC(vb[n]), acc[4 + m][n]); \
    __builtin_amdgcn_s_setprio(0); \
    BAR(); \
  }

// GEMM1: 256 tokens x (128 f-cols x {gate,up}), K = DIM = 2048 (64 chunks).
__global__ __launch_bounds__(512, 2) void gemm_gateup_kernel(
    const ushort* __restrict__ xb, const ushort* __restrict__ wgt,
    const ushort* __restrict__ wut, const int* __restrict__ lpk,
    const int* __restrict__ stats, ushort* __restrict__ h)
{
  int e = blockIdx.z;
  int Me = stats[e];
  int tm = blockIdx.x;
  if (tm * 256 >= Me) return;
  int abase = stats[16 + e];
  int tn = blockIdx.y;

  extern __shared__ char sm[];
  int* rofsLds = (int*)(sm + 131072);

  int tid = threadIdx.x, lane = tid & 63, wv = tid >> 6;
  if (tid < 256) {
    int gr = tm * 256 + tid;
    int pk = lpk[abase + ((gr < Me) ? gr : 0)];
    rofsLds[tid] = (pk >> 1) * (DIM * 2);   // byte offset into xb
  }
  __syncthreads();

  // ---- per-lane staging sources (pre-swizzled) ----
  int q1 = wv * 16 + (lane >> 3);
  int v1 = (lane & 7) ^ (q1 & 7);
  int rowA1 = 2 * q1 + (v1 >> 2);           // in [wv*32, wv*32+32)
  int rowA2 = rowA1 + 16;
  int ks16 = (v1 & 3) * 16;                 // k-slot byte offset
  const char* aS1 = (const char*)xb + rofsLds[rowA1] + ks16;
  const char* aS2 = (const char*)xb + rofsLds[rowA2] + ks16;
  const char* wB = (wv < 4) ? (const char*)wgt : (const char*)wut;
  const char* bS1 = wB + ((size_t)e * FFN + tn * 128 + (rowA1 & 127)) * (size_t)(DIM * 2) + ks16;
  const char* bS2 = wB + ((size_t)e * FFN + tn * 128 + (rowA2 & 127)) * (size_t)(DIM * 2) + ks16;

  // ---- ds_read addresses ----
  int wm = wv >> 2, wn = wv & 3, s = lane >> 4;
  int adA0[4], adA1[4], adB[4];
  #pragma unroll
  for (int m = 0; m < 4; ++m) {
    adA0[m] = swz(wm * 128 +       m * 16 + (lane & 15), s);
    adA1[m] = swz(wm * 128 + 64 +  m * 16 + (lane & 15), s);
  }
  #pragma unroll
  for (int n = 0; n < 4; ++n) adB[n] = 16384 + swz(wn * 64 + n * 16 + (lane & 15), s);

  f32x4 acc[8][4];
  #pragma unroll
  for (int m = 0; m < 8; ++m)
    #pragma unroll
    for (int n = 0; n < 4; ++n) acc[m][n] = (f32x4){0, 0, 0, 0};

  // ---- prologue: chunks 0,1,2 ----
  STAGE_A(0); STAGE_B(0);
  STAGE_A(1); STAGE_B(1);
  STAGE_A(2); STAGE_B(2);

  KLOOP(64);

  // ---- epilogue: exchange u via LDS, fuse SiLU ----
  __syncthreads();
  float* u_lds = (float*)sm;                 // [256][128] f32 = 128KB
  if (wn >= 2) {
    #pragma unroll
    for (int m = 0; m < 8; ++m) {
      int rb = wm * 128 + (m >> 2) * 64 + (m & 3) * 16 + (lane >> 4) * 4;
      #pragma unroll
      for (int n = 0; n < 4; ++n) {
        int fl = (wn - 2) * 64 + n * 16 + (lane & 15);
        #pragma unroll
        for (int r = 0; r < 4; ++r) u_lds[(rb + r) * 128 + fl] = acc[m][n][r];
      }
    }
  }
  __syncthreads();
  if (wn < 2) {
    #pragma unroll
    for (int m = 0; m < 8; ++m) {
      int rb = wm * 128 + (m >> 2) * 64 + (m & 3) * 16 + (lane >> 4) * 4;
      #pragma unroll
      for (int n = 0; n < 4; ++n) {
        int fl = wn * 64 + n * 16 + (lane & 15);
        #pragma unroll
        for (int r = 0; r < 4; ++r) {
          int row = rb + r;
          if (tm * 256 + row < Me) {
            float g = acc[m][n][r];
            float u = u_lds[row * 128 + fl];
            h[(size_t)(abase + tm * 256 + row) * FFN + tn * 128 + fl] =
                f2bf(g * u / (1.f + __expf(-g)));
          }
        }
      }
    }
  }
}

// GEMM2: 256 expert-token rows x 256 d-cols, K = FFN = 1408 (44 chunks).
__global__ __launch_bounds__(512, 2) void gemm_down_kernel(
    const ushort* __restrict__ h, const ushort* __restrict__ wdt,
    const int* __restrict__ lpk, const float* __restrict__ lw,
    const int* __restrict__ stats, float* __restrict__ out)
{
  int e = blockIdx.z;
  int Me = stats[e];
  int tm = blockIdx.x;
  if (tm * 256 >= Me) return;
  int abase = stats[16 + e];
  int tn = blockIdx.y;

  extern __shared__ char sm[];
  int*   pkl = (int*)(sm + 131072);
  float* wl  = (float*)(sm + 132096);

  int tid = threadIdx.x, lane = tid & 63, wv = tid >> 6;
  if (tid < 256) {
    int gr = tm * 256 + tid;
    pkl[tid] = (gr < Me) ? lpk[abase + gr] : 0;
    wl[tid]  = (gr < Me) ? lw[abase + gr] : 0.f;
  }
  __syncthreads();

  int q1 = wv * 16 + (lane >> 3);
  int v1 = (lane & 7) ^ (q1 & 7);
  int rowA1 = 2 * q1 + (v1 >> 2);
  int rowA2 = rowA1 + 16;
  int ks16 = (v1 & 3) * 16;
  int ar1 = abase + tm * 256 + rowA1; if (ar1 > 2 * N_TOK - 1) ar1 = 2 * N_TOK - 1;
  int ar2 = abase + tm * 256 + rowA2; if (ar2 > 2 * N_TOK - 1) ar2 = 2 * N_TOK - 1;
  const char* aS1 = (const char*)h + (size_t)ar1 * (FFN * 2) + ks16;
  const char* aS2 = (const char*)h + (size_t)ar2 * (FFN * 2) + ks16;
  const char* bS1 = (const char*)wdt + ((size_t)e * DIM + tn * 256 + rowA1) * (size_t)(FFN * 2) + ks16;
  const char* bS2 = (const char*)wdt + ((size_t)e * DIM + tn * 256 + rowA2) * (size_t)(FFN * 2) + ks16;

  int wm = wv >> 2, wn = wv & 3, s = lane >> 4;
  int adA0[4], adA1[4], adB[4];
  #pragma unroll
  for (int m = 0; m < 4; ++m) {
    adA0[m] = swz(wm * 128 +       m * 16 + (lane & 15), s);
    adA1[m] = swz(wm * 128 + 64 +  m * 16 + (lane & 15), s);
  }
  #pragma unroll
  for (int n = 0; n < 4; ++n) adB[n] = 16384 + swz(wn * 64 + n * 16 + (lane & 15), s);

  f32x4 acc[8][4];
  #pragma unroll
  for (int m = 0; m < 8; ++m)
    #pragma unroll
    for (int n = 0; n < 4; ++n) acc[m][n] = (f32x4){0, 0, 0, 0};

  STAGE_A(0); STAGE_B(0);
  STAGE_A(1); STAGE_B(1);
  STAGE_A(2); STAGE_B(2);

  KLOOP(44);

  int c = lane & 15, r0 = (lane >> 4) * 4;
  #pragma unroll
  for (int m = 0; m < 8; ++m) {
    int rb = wm * 128 + (m >> 2) * 64 + (m & 3) * 16 + r0;
    #pragma unroll
    for (int n = 0; n < 4; ++n) {
      int col = tn * 256 + wn * 64 + n * 16 + c;
      #pragma unroll
      for (int r = 0; r < 4; ++r) {
        int row = rb + r;
        if (tm * 256 + row < Me) {
          int t = pkl[row] >> 1;
          unsafeAtomicAdd(&out[(size_t)t * DIM + col], wl[row] * acc[m][n][r]);
        }
      }
    }
  }
}

extern "C" void kernel_launch(void* const* d_in, const int* in_sizes, int n_in,
                              void* d_out, int out_size, void* d_ws, size_t ws_size,
                              hipStream_t stream)
{
  const float* x  = (const float*)d_in[0];
  const float* rw = (const float*)d_in[1];
  const float* wg = (const float*)d_in[2];
  const float* wu = (const float*)d_in[3];
  const float* wd = (const float*)d_in[4];
  float* out = (float*)d_out;

  char* ws = (char*)d_ws;
  ushort* xb   = (ushort*)(ws + X_OFF);
  ushort* wgt  = (ushort*)(ws + WG_OFF);
  ushort* wut  = (ushort*)(ws + WU_OFF);
  ushort* wdt  = (ushort*)(ws + WD_OFF);
  ushort* hbuf = (ushort*)(ws + H_OFF);
  int*    lpk  = (int*)(ws + LPK_OFF);
  float*  lw   = (float*)(ws + LW_OFF);
  int*    topi = (int*)(ws + TI_OFF);
  float*  topw = (float*)(ws + TW_OFF);
  int*    stats = (int*)(ws + ST_OFF);
  unsigned long long* psum = (unsigned long long*)(ws + ST_OFF + 96);

  hipMemsetAsync(d_out, 0, (size_t)out_size * sizeof(float), stream);
  hipMemsetAsync(ws + ST_OFF, 0, 160, stream);

  router_kernel<<<512, 256, 0, stream>>>(x, rw, xb, topi, topw, stats, psum);
  scan_aux_kernel<<<1, 64, 0, stream>>>(stats, psum, out + (size_t)out_size - 1);
  place_kernel<<<32, 256, 0, stream>>>(topi, topw, stats, lpk, lw);

  conv_t_kernel<<<dim3(44, 64, 8), 256, 0, stream>>>(wg, wgt, DIM, FFN);
  conv_t_kernel<<<dim3(44, 64, 8), 256, 0, stream>>>(wu, wut, DIM, FFN);
  conv_t_kernel<<<dim3(64, 44, 8), 256, 0, stream>>>(wd, wdt, FFN, DIM);

  gemm_gateup_kernel<<<dim3(32, 11, 8), 512, 132096, stream>>>(xb, wgt, wut, lpk, stats, hbuf);
  gemm_down_kernel<<<dim3(32, 8, 8), 512, 133120, stream>>>(hbuf, wdt, lpk, lw, stats, out);
}

// Round 5
// 1258.781 us; speedup vs baseline: 1.0456x; 1.0456x over previous
//
#include <hip/hip_runtime.h>

#define N_TOK 8192
#define DIM   2048
#define FFN   1408
#define NEXP  8

// ---------- ws layout (bytes) ----------
#define X_OFF   0ull                          // x bf16 [N][D]
#define P1_OFF  33554432ull                   // packed wg+wu [e][tn11][j64][1024]x16B = 92,274,688
#define P2_OFF  125829120ull                  // packed wd    [e][tn8][j44][1024]x16B = 46,137,344
#define H_OFF   171966464ull                  // h bf16 [2N][F]
#define LPK_OFF 218103808ull
#define LW_OFF  218169344ull
#define TI_OFF  218234880ull
#define TW_OFF  218267648ull
#define ST_OFF  218300416ull

typedef __bf16 bf16x8 __attribute__((ext_vector_type(8)));
typedef float  f32x4  __attribute__((ext_vector_type(4)));
typedef int    int4v  __attribute__((ext_vector_type(4)));
typedef __attribute__((address_space(1))) void as1_void;
typedef __attribute__((address_space(3))) void as3_void;

__device__ __forceinline__ void gload16(const void* g, void* l) {
  __builtin_amdgcn_global_load_lds((as1_void*)g, (as3_void*)l, 16, 0, 0);
}

__device__ __forceinline__ ushort f2bf(float f) {
  unsigned u = __builtin_bit_cast(unsigned, f);
  u += 0x7FFFu + ((u >> 16) & 1u);
  return (ushort)(u >> 16);
}

__device__ __forceinline__ int4v dsread(int addr) {
  int4v d;
  asm volatile("ds_read_b128 %0, %1" : "=v"(d) : "v"(addr));
  return d;
}

#define WAITL() do { asm volatile("s_waitcnt lgkmcnt(0)" ::: "memory"); \
                     __builtin_amdgcn_sched_barrier(0); } while (0)
#define BAR()   __builtin_amdgcn_s_barrier()
#define MFMA16(a, b, c) __builtin_amdgcn_mfma_f32_16x16x32_bf16(a, b, c, 0, 0, 0)
#define BC(x) __builtin_bit_cast(bf16x8, x)

// LDS unit layout: [row-pair q][8 pos of 16B], pos p = (((row&1)<<2)|slot) ^ (q&7).
__device__ __forceinline__ int swz(int row, int s) {
  int q = row >> 1;
  int p = (((row & 1) << 2) | s) ^ (q & 7);
  return q * 128 + p * 16;
}

// ---------------- router ----------------
__global__ __launch_bounds__(256) void router_kernel(
    const float* __restrict__ x, const float* __restrict__ rw,
    ushort* __restrict__ xb, int* __restrict__ topi, float* __restrict__ topw,
    int* __restrict__ cnt, unsigned long long* __restrict__ psum)
{
  int tid = threadIdx.x, lane = tid & 63, wv = tid >> 6;
  __shared__ float sP[4][8];
  __shared__ int   sC[4][8];
  float pacc[8]; int cacc[8];
  #pragma unroll
  for (int e = 0; e < 8; ++e) { pacc[e] = 0.f; cacc[e] = 0; }

  #pragma unroll 1
  for (int it = 0; it < 4; ++it) {
    int t = blockIdx.x * 16 + wv * 4 + it;
    const float4* xr = (const float4*)(x + (size_t)t * DIM);
    float acc[8];
    #pragma unroll
    for (int e = 0; e < 8; ++e) acc[e] = 0.f;
    #pragma unroll 1
    for (int i = 0; i < 8; ++i) {
      int j = i * 64 + lane;
      float4 v = xr[j];
      ushort4 o; o.x = f2bf(v.x); o.y = f2bf(v.y); o.z = f2bf(v.z); o.w = f2bf(v.w);
      *(ushort4*)(xb + (size_t)t * DIM + (size_t)j * 4) = o;
      const float* rr = rw + (size_t)j * 32;
      #pragma unroll
      for (int c = 0; c < 4; ++c) {
        float xv = (&v.x)[c];
        const float4* r4 = (const float4*)(rr + c * 8);
        float4 q0 = r4[0], q1 = r4[1];
        acc[0] += xv * q0.x; acc[1] += xv * q0.y; acc[2] += xv * q0.z; acc[3] += xv * q0.w;
        acc[4] += xv * q1.x; acc[5] += xv * q1.y; acc[6] += xv * q1.z; acc[7] += xv * q1.w;
      }
    }
    #pragma unroll
    for (int off = 32; off; off >>= 1) {
      #pragma unroll
      for (int e = 0; e < 8; ++e) acc[e] += __shfl_xor(acc[e], off);
    }
    float m = acc[0];
    #pragma unroll
    for (int e = 1; e < 8; ++e) m = fmaxf(m, acc[e]);
    float p[8], s = 0.f;
    #pragma unroll
    for (int e = 0; e < 8; ++e) { p[e] = __expf(acc[e] - m); s += p[e]; }
    float inv = 1.f / s;
    int i1 = 0; float p1 = p[0];
    #pragma unroll
    for (int e = 1; e < 8; ++e) if (p[e] > p1) { p1 = p[e]; i1 = e; }
    int i2 = -1; float p2 = -1.f;
    #pragma unroll
    for (int e = 0; e < 8; ++e) if (e != i1 && p[e] > p2) { p2 = p[e]; i2 = e; }
    float w1 = p1 / (p1 + p2);
    if (lane == 0) {
      topi[t] = i1 | (i2 << 8);
      topw[t] = w1;
      #pragma unroll
      for (int e = 0; e < 8; ++e) pacc[e] += p[e] * inv;
      cacc[i1]++; cacc[i2]++;
    }
  }
  if (lane == 0) {
    #pragma unroll
    for (int e = 0; e < 8; ++e) { sP[wv][e] = pacc[e]; sC[wv][e] = cacc[e]; }
  }
  __syncthreads();
  if (tid < 8) {
    float ps = sP[0][tid] + sP[1][tid] + sP[2][tid] + sP[3][tid];
    int   cs = sC[0][tid] + sC[1][tid] + sC[2][tid] + sC[3][tid];
    atomicAdd(&cnt[tid], cs);
    atomicAdd(&psum[tid], (unsigned long long)((double)ps * 1099511627776.0));
  }
}

// ---------------- scan + aux ----------------
__global__ void scan_aux_kernel(int* __restrict__ stats,
                                const unsigned long long* __restrict__ psum,
                                float* __restrict__ aux_out)
{
  if (threadIdx.x == 0 && blockIdx.x == 0) {
    int b = 0;
    for (int e = 0; e < 8; ++e) { stats[16 + e] = b; stats[8 + e] = b; b += stats[e]; }
    double s = 0.0;
    for (int e = 0; e < 8; ++e)
      s += (double)stats[e] * ((double)psum[e] * (1.0 / 1099511627776.0));
    aux_out[0] = (float)(4.0 * s / ((double)N_TOK * (double)N_TOK));
  }
}

// ---------------- placement ----------------
__global__ __launch_bounds__(256) void place_kernel(
    const int* __restrict__ topi, const float* __restrict__ topw,
    int* __restrict__ stats, int* __restrict__ lpk, float* __restrict__ lw)
{
  int t = blockIdx.x * 256 + threadIdx.x;
  if (t >= N_TOK) return;
  int pk = topi[t];
  int e1 = pk & 0xff, e2 = (pk >> 8) & 0xff;
  float w1 = topw[t];
  int p1 = atomicAdd(&stats[8 + e1], 1);
  lpk[p1] = (t << 1); lw[p1] = w1;
  int p2 = atomicAdd(&stats[8 + e2], 1);
  lpk[p2] = (t << 1) | 1; lw[p2] = 1.f - w1;
}

// ---------------- pack wg+wu: f32 [E][D][F] -> chunk-packed bf16 ----------------
// p1 unit L of (e,tn,j): row = 2q+(v>>2), slot = v&3 (q=L>>3, v=(L&7)^(q&7));
// data = (row<128 ? wg : wu)[e][j*32+slot*8 .. +8][tn*128 + (row&127)]
__global__ __launch_bounds__(256) void pack_gu_kernel(
    const float* __restrict__ wg, const float* __restrict__ wu,
    ushort* __restrict__ p1)
{
  int j = blockIdx.x, tn = blockIdx.y, e = blockIdx.z;
  __shared__ float tg[32][132];
  __shared__ float tu[32][132];
  int t = threadIdx.x;
  const float* gsrc = wg + ((size_t)e * DIM + j * 32) * FFN + tn * 128;
  const float* usrc = wu + ((size_t)e * DIM + j * 32) * FFN + tn * 128;
  #pragma unroll
  for (int k = 0; k < 4; ++k) {
    int v = t + k * 256;
    int d = v >> 5, fq = v & 31;
    *(float4*)&tg[d][fq * 4] = *(const float4*)(gsrc + (size_t)d * FFN + fq * 4);
    *(float4*)&tu[d][fq * 4] = *(const float4*)(usrc + (size_t)d * FFN + fq * 4);
  }
  __syncthreads();
  ushort* dst = p1 + (((size_t)(e * 11 + tn) * 64 + j) * 1024) * 8;
  #pragma unroll
  for (int k = 0; k < 4; ++k) {
    int L = t + k * 256;
    int q = L >> 3, v = (L & 7) ^ (q & 7);
    int row = 2 * q + (v >> 2), slot = v & 3;
    const float* src = (row < 128) ? &tg[slot * 8][row] : &tu[slot * 8][row - 128];
    ushort u8[8];
    #pragma unroll
    for (int i = 0; i < 8; ++i) u8[i] = f2bf(src[i * 132]);
    *(ushort4*)(dst + (size_t)L * 8)     = *(ushort4*)&u8[0];
    *(ushort4*)(dst + (size_t)L * 8 + 4) = *(ushort4*)&u8[4];
  }
}

// ---------------- pack wd: f32 [E][F][D] -> chunk-packed bf16 ----------------
// p2 unit L of (e,tn,j): row,slot as above;
// data = wd[e][j*32+slot*8 .. +8][tn*256 + row]
__global__ __launch_bounds__(256) void pack_d_kernel(
    const float* __restrict__ wd, ushort* __restrict__ p2)
{
  int j = blockIdx.x, tn = blockIdx.y, e = blockIdx.z;
  __shared__ float t2[32][260];
  int t = threadIdx.x;
  const float* src0 = wd + ((size_t)e * FFN + j * 32) * DIM + tn * 256;
  #pragma unroll
  for (int k = 0; k < 8; ++k) {
    int v = t + k * 256;
    int f = v >> 6, dq = v & 63;
    *(float4*)&t2[f][dq * 4] = *(const float4*)(src0 + (size_t)f * DIM + dq * 4);
  }
  __syncthreads();
  ushort* dst = p2 + (((size_t)(e * 8 + tn) * 44 + j) * 1024) * 8;
  #pragma unroll
  for (int k = 0; k < 4; ++k) {
    int L = t + k * 256;
    int q = L >> 3, v = (L & 7) ^ (q & 7);
    int row = 2 * q + (v >> 2), slot = v & 3;
    const float* src = &t2[slot * 8][row];
    ushort u8[8];
    #pragma unroll
    for (int i = 0; i < 8; ++i) u8[i] = f2bf(src[i * 260]);
    *(ushort4*)(dst + (size_t)L * 8)     = *(ushort4*)&u8[0];
    *(ushort4*)(dst + (size_t)L * 8 + 4) = *(ushort4*)&u8[4];
  }
}

// =====================================================================
// GEMM machinery: BM=BN=256, BK=32, ring of 4 LDS slots (32KB each),
// prefetch distance 3, 8 waves (2M x 4N), vmcnt(10)/8/4/0 schedule.
// B staged from chunk-packed weights (fully contiguous 16KB/chunk).
// =====================================================================

#define STAGE_A(J) do { size_t kb_ = (size_t)(J) * 64; int d_ = ((J) & 3) * 32768 + wv * 2048; \
  gload16(aS1 + kb_, sm + d_); gload16(aS2 + kb_, sm + d_ + 1024); } while (0)
#define STAGE_B(J) do { size_t off_ = (size_t)(J) * 16384; int d_ = ((J) & 3) * 32768 + 16384 + wv * 2048; \
  gload16(bP + off_, sm + d_); gload16(bP + off_ + 1024, sm + d_ + 1024); } while (0)

#define VMW(J, NCH) do { \
  if ((J) < (NCH) - 3)       asm volatile("s_waitcnt vmcnt(10)" ::: "memory"); \
  else if ((J) == (NCH) - 3) asm volatile("s_waitcnt vmcnt(8)"  ::: "memory"); \
  else if ((J) == (NCH) - 2) asm volatile("s_waitcnt vmcnt(4)"  ::: "memory"); \
  else                       asm volatile("s_waitcnt vmcnt(0)"  ::: "memory"); \
} while (0)

#define KLOOP(NCH) \
  for (int j = 0; j < (NCH); ++j) { \
    int sb = (j & 3) * 32768; \
    if (j + 3 < (NCH)) STAGE_A(j + 3); \
    VMW(j, (NCH)); \
    BAR(); \
    int4v vb[4], va[4]; \
    _Pragma("unroll") for (int n = 0; n < 4; ++n) vb[n] = dsread(sb + adB[n]); \
    _Pragma("unroll") for (int m = 0; m < 4; ++m) va[m] = dsread(sb + adA0[m]); \
    WAITL(); \
    __builtin_amdgcn_s_setprio(1); \
    _Pragma("unroll") for (int m = 0; m < 4; ++m) \
      _Pragma("unroll") for (int n = 0; n < 4; ++n) \
        acc[m][n] = MFMA16(BC(va[m]), BC(vb[n]), acc[m][n]); \
    __builtin_amdgcn_s_setprio(0); \
    if (j + 3 < (NCH)) STAGE_B(j + 3); \
    _Pragma("unroll") for (int m = 0; m < 4; ++m) va[m] = dsread(sb + adA1[m]); \
    WAITL(); \
    __builtin_amdgcn_s_setprio(1); \
    _Pragma("unroll") for (int m = 0; m < 4; ++m) \
      _Pragma("unroll") for (int n = 0; n < 4; ++n) \
        acc[4 + m][n] = MFMA16(BC(va[m]), BC(vb[n]), acc[4 + m][n]); \
    __builtin_amdgcn_s_setprio(0); \
    BAR(); \
  }

// GEMM1: 256 tokens x (128 f-cols x {gate,up}), K = DIM (64 chunks).
__global__ __launch_bounds__(512, 2) void gemm_gateup_kernel(
    const ushort* __restrict__ xb, const ushort* __restrict__ p1,
    const int* __restrict__ lpk, const int* __restrict__ stats,
    ushort* __restrict__ h)
{
  int e = blockIdx.z;
  int Me = stats[e];
  int tm = blockIdx.x;
  if (tm * 256 >= Me) return;
  int abase = stats[16 + e];
  int tn = blockIdx.y;

  extern __shared__ char sm[];
  int* rofsLds = (int*)(sm + 131072);

  int tid = threadIdx.x, lane = tid & 63, wv = tid >> 6;
  if (tid < 256) {
    int gr = tm * 256 + tid;
    int pk = lpk[abase + ((gr < Me) ? gr : 0)];
    rofsLds[tid] = (pk >> 1) * (DIM * 2);
  }
  __syncthreads();

  // A staging sources (token gather, pre-swizzled)
  int q1 = wv * 16 + (lane >> 3);
  int v1 = (lane & 7) ^ (q1 & 7);
  int rowA1 = 2 * q1 + (v1 >> 2);
  int rowA2 = rowA1 + 16;
  int ks16 = (v1 & 3) * 16;
  const char* aS1 = (const char*)xb + rofsLds[rowA1] + ks16;
  const char* aS2 = (const char*)xb + rofsLds[rowA2] + ks16;
  // B staging source: packed, contiguous
  const char* bP = (const char*)p1 + (size_t)(e * 11 + tn) * 64 * 16384 + (wv * 128 + lane) * 16;

  int wm = wv >> 2, wn = wv & 3, s = lane >> 4;
  int adA0[4], adA1[4], adB[4];
  #pragma unroll
  for (int m = 0; m < 4; ++m) {
    adA0[m] = swz(wm * 128 +      m * 16 + (lane & 15), s);
    adA1[m] = swz(wm * 128 + 64 + m * 16 + (lane & 15), s);
  }
  #pragma unroll
  for (int n = 0; n < 4; ++n) adB[n] = 16384 + swz(wn * 64 + n * 16 + (lane & 15), s);

  f32x4 acc[8][4];
  #pragma unroll
  for (int m = 0; m < 8; ++m)
    #pragma unroll
    for (int n = 0; n < 4; ++n) acc[m][n] = (f32x4){0, 0, 0, 0};

  STAGE_A(0); STAGE_B(0);
  STAGE_A(1); STAGE_B(1);
  STAGE_A(2); STAGE_B(2);

  KLOOP(64);

  // epilogue: exchange u via LDS, fuse SiLU
  __syncthreads();
  float* u_lds = (float*)sm;                 // [256][128] f32
  if (wn >= 2) {
    #pragma unroll
    for (int m = 0; m < 8; ++m) {
      int rb = wm * 128 + (m >> 2) * 64 + (m & 3) * 16 + (lane >> 4) * 4;
      #pragma unroll
      for (int n = 0; n < 4; ++n) {
        int fl = (wn - 2) * 64 + n * 16 + (lane & 15);
        #pragma unroll
        for (int r = 0; r < 4; ++r) u_lds[(rb + r) * 128 + fl] = acc[m][n][r];
      }
    }
  }
  __syncthreads();
  if (wn < 2) {
    #pragma unroll
    for (int m = 0; m < 8; ++m) {
      int rb = wm * 128 + (m >> 2) * 64 + (m & 3) * 16 + (lane >> 4) * 4;
      #pragma unroll
      for (int n = 0; n < 4; ++n) {
        int fl = wn * 64 + n * 16 + (lane & 15);
        #pragma unroll
        for (int r = 0; r < 4; ++r) {
          int row = rb + r;
          if (tm * 256 + row < Me) {
            float g = acc[m][n][r];
            float u = u_lds[row * 128 + fl];
            h[(size_t)(abase + tm * 256 + row) * FFN + tn * 128 + fl] =
                f2bf(g * u / (1.f + __expf(-g)));
          }
        }
      }
    }
  }
}

// GEMM2: 256 expert-token rows x 256 d-cols, K = FFN (44 chunks).
__global__ __launch_bounds__(512, 2) void gemm_down_kernel(
    const ushort* __restrict__ h, const ushort* __restrict__ p2,
    const int* __restrict__ lpk, const float* __restrict__ lw,
    const int* __restrict__ stats, float* __restrict__ out)
{
  int e = blockIdx.z;
  int Me = stats[e];
  int tm = blockIdx.x;
  if (tm * 256 >= Me) return;
  int abase = stats[16 + e];
  int tn = blockIdx.y;

  extern __shared__ char sm[];
  int*   pkl = (int*)(sm + 131072);
  float* wl  = (float*)(sm + 132096);

  int tid = threadIdx.x, lane = tid & 63, wv = tid >> 6;
  if (tid < 256) {
    int gr = tm * 256 + tid;
    pkl[tid] = (gr < Me) ? lpk[abase + gr] : 0;
    wl[tid]  = (gr < Me) ? lw[abase + gr] : 0.f;
  }
  __syncthreads();

  int q1 = wv * 16 + (lane >> 3);
  int v1 = (lane & 7) ^ (q1 & 7);
  int rowA1 = 2 * q1 + (v1 >> 2);
  int rowA2 = rowA1 + 16;
  int ks16 = (v1 & 3) * 16;
  int ar1 = abase + tm * 256 + rowA1; if (ar1 > 2 * N_TOK - 1) ar1 = 2 * N_TOK - 1;
  int ar2 = abase + tm * 256 + rowA2; if (ar2 > 2 * N_TOK - 1) ar2 = 2 * N_TOK - 1;
  const char* aS1 = (const char*)h + (size_t)ar1 * (FFN * 2) + ks16;
  const char* aS2 = (const char*)h + (size_t)ar2 * (FFN * 2) + ks16;
  const char* bP = (const char*)p2 + (size_t)(e * 8 + tn) * 44 * 16384 + (wv * 128 + lane) * 16;

  int wm = wv >> 2, wn = wv & 3, s = lane >> 4;
  int adA0[4], adA1[4], adB[4];
  #pragma unroll
  for (int m = 0; m < 4; ++m) {
    adA0[m] = swz(wm * 128 +      m * 16 + (lane & 15), s);
    adA1[m] = swz(wm * 128 + 64 + m * 16 + (lane & 15), s);
  }
  #pragma unroll
  for (int n = 0; n < 4; ++n) adB[n] = 16384 + swz(wn * 64 + n * 16 + (lane & 15), s);

  f32x4 acc[8][4];
  #pragma unroll
  for (int m = 0; m < 8; ++m)
    #pragma unroll
    for (int n = 0; n < 4; ++n) acc[m][n] = (f32x4){0, 0, 0, 0};

  STAGE_A(0); STAGE_B(0);
  STAGE_A(1); STAGE_B(1);
  STAGE_A(2); STAGE_B(2);

  KLOOP(44);

  int c = lane & 15, r0 = (lane >> 4) * 4;
  #pragma unroll
  for (int m = 0; m < 8; ++m) {
    int rb = wm * 128 + (m >> 2) * 64 + (m & 3) * 16 + r0;
    #pragma unroll
    for (int n = 0; n < 4; ++n) {
      int col = tn * 256 + wn * 64 + n * 16 + c;
      #pragma unroll
      for (int r = 0; r < 4; ++r) {
        int row = rb + r;
        if (tm * 256 + row < Me) {
          int t = pkl[row] >> 1;
          unsafeAtomicAdd(&out[(size_t)t * DIM + col], wl[row] * acc[m][n][r]);
        }
      }
    }
  }
}

extern "C" void kernel_launch(void* const* d_in, const int* in_sizes, int n_in,
                              void* d_out, int out_size, void* d_ws, size_t ws_size,
                              hipStream_t stream)
{
  const float* x  = (const float*)d_in[0];
  const float* rw = (const float*)d_in[1];
  const float* wg = (const float*)d_in[2];
  const float* wu = (const float*)d_in[3];
  const float* wd = (const float*)d_in[4];
  float* out = (float*)d_out;

  char* ws = (char*)d_ws;
  ushort* xb   = (ushort*)(ws + X_OFF);
  ushort* p1   = (ushort*)(ws + P1_OFF);
  ushort* p2   = (ushort*)(ws + P2_OFF);
  ushort* hbuf = (ushort*)(ws + H_OFF);
  int*    lpk  = (int*)(ws + LPK_OFF);
  float*  lw   = (float*)(ws + LW_OFF);
  int*    topi = (int*)(ws + TI_OFF);
  float*  topw = (float*)(ws + TW_OFF);
  int*    stats = (int*)(ws + ST_OFF);
  unsigned long long* psum = (unsigned long long*)(ws + ST_OFF + 96);

  hipMemsetAsync(d_out, 0, (size_t)out_size * sizeof(float), stream);
  hipMemsetAsync(ws + ST_OFF, 0, 160, stream);

  router_kernel<<<512, 256, 0, stream>>>(x, rw, xb, topi, topw, stats, psum);
  scan_aux_kernel<<<1, 64, 0, stream>>>(stats, psum, out + (size_t)out_size - 1);
  place_kernel<<<32, 256, 0, stream>>>(topi, topw, stats, lpk, lw);

  pack_gu_kernel<<<dim3(64, 11, 8), 256, 0, stream>>>(wg, wu, p1);
  pack_d_kernel<<<dim3(44, 8, 8), 256, 0, stream>>>(wd, p2);

  gemm_gateup_kernel<<<dim3(32, 11, 8), 512, 132096, stream>>>(xb, p1, lpk, stats, hbuf);
  gemm_down_kernel<<<dim3(32, 8, 8), 512, 133120, stream>>>(hbuf, p2, lpk, lw, stats, out);
}

// Round 6
// 810.281 us; speedup vs baseline: 1.6243x; 1.5535x over previous
//
#include <hip/hip_runtime.h>

#define N_TOK 8192
#define DIM   2048
#define FFN   1408

// ---------- ws layout (bytes) ----------
#define XGP_OFF 0ull                  // packed x images: 136 tiles x 64 j x 8192
#define P1_OFF  71303168ull           // packed gate+up: 8 x 22 x 64 x 8192
#define P2_OFF  163577856ull          // packed down:    8 x 16 x 44 x 8192
#define HP_OFF  209715200ull          // packed h images: 136 x 44 x 8192
#define LPK_OFF 258736128ull          // [16384] int
#define LW_OFF  258801664ull          // [16384] f32
#define TI_OFF  258867200ull          // [8192] int
#define TW_OFF  258899968ull          // [8192] f32
#define ST_OFF  258932736ull          // ints: cnt8 cur8 abase8 tbase8 ttot ; psum u64[8] @+192

typedef __bf16 bf16x8 __attribute__((ext_vector_type(8)));
typedef float  f32x4  __attribute__((ext_vector_type(4)));
typedef int    int4v  __attribute__((ext_vector_type(4)));
typedef __attribute__((address_space(1))) void as1_void;
typedef __attribute__((address_space(3))) void as3_void;

__device__ __forceinline__ void gload16(const void* g, void* l) {
  __builtin_amdgcn_global_load_lds((as1_void*)g, (as3_void*)l, 16, 0, 0);
}

__device__ __forceinline__ ushort f2bf(float f) {
  unsigned u = __builtin_bit_cast(unsigned, f);
  u += 0x7FFFu + ((u >> 16) & 1u);
  return (ushort)(u >> 16);
}

__device__ __forceinline__ int4v dsread(int addr) {
  int4v d;
  asm volatile("ds_read_b128 %0, %1" : "=v"(d) : "v"(addr));
  return d;
}

#define WAITL() do { asm volatile("s_waitcnt lgkmcnt(0)" ::: "memory"); \
                     __builtin_amdgcn_sched_barrier(0); } while (0)
#define BAR()   __builtin_amdgcn_s_barrier()
#define MFMA16(a, b, c) __builtin_amdgcn_mfma_f32_16x16x32_bf16(a, b, c, 0, 0, 0)
#define BC(x) __builtin_bit_cast(bf16x8, x)

// 8KB unit = 128 rows x 32 k bf16. 16B piece (row, s): q=row>>1,
// p = (((row&1)<<2)|s) ^ (q&7); byte = q*128 + p*16.
__device__ __forceinline__ int swz(int row, int s) {
  int q = row >> 1;
  int p = (((row & 1) << 2) | s) ^ (q & 7);
  return q * 128 + p * 16;
}

// ---------------- router ----------------
__global__ __launch_bounds__(256) void router_kernel(
    const float* __restrict__ x, const float* __restrict__ rw,
    int* __restrict__ topi, float* __restrict__ topw,
    int* __restrict__ cnt, unsigned long long* __restrict__ psum)
{
  int tid = threadIdx.x, lane = tid & 63, wv = tid >> 6;
  __shared__ float sP[4][8];
  __shared__ int   sC[4][8];
  float pacc[8]; int cacc[8];
  #pragma unroll
  for (int e = 0; e < 8; ++e) { pacc[e] = 0.f; cacc[e] = 0; }

  #pragma unroll 1
  for (int it = 0; it < 4; ++it) {
    int t = blockIdx.x * 16 + wv * 4 + it;
    const float4* xr = (const float4*)(x + (size_t)t * DIM);
    float acc[8];
    #pragma unroll
    for (int e = 0; e < 8; ++e) acc[e] = 0.f;
    #pragma unroll 1
    for (int i = 0; i < 8; ++i) {
      int j = i * 64 + lane;
      float4 v = xr[j];
      const float* rr = rw + (size_t)j * 32;
      #pragma unroll
      for (int c = 0; c < 4; ++c) {
        float xv = (&v.x)[c];
        const float4* r4 = (const float4*)(rr + c * 8);
        float4 q0 = r4[0], q1 = r4[1];
        acc[0] += xv * q0.x; acc[1] += xv * q0.y; acc[2] += xv * q0.z; acc[3] += xv * q0.w;
        acc[4] += xv * q1.x; acc[5] += xv * q1.y; acc[6] += xv * q1.z; acc[7] += xv * q1.w;
      }
    }
    #pragma unroll
    for (int off = 32; off; off >>= 1) {
      #pragma unroll
      for (int e = 0; e < 8; ++e) acc[e] += __shfl_xor(acc[e], off);
    }
    float m = acc[0];
    #pragma unroll
    for (int e = 1; e < 8; ++e) m = fmaxf(m, acc[e]);
    float p[8], s = 0.f;
    #pragma unroll
    for (int e = 0; e < 8; ++e) { p[e] = __expf(acc[e] - m); s += p[e]; }
    float inv = 1.f / s;
    int i1 = 0; float p1 = p[0];
    #pragma unroll
    for (int e = 1; e < 8; ++e) if (p[e] > p1) { p1 = p[e]; i1 = e; }
    int i2 = -1; float p2 = -1.f;
    #pragma unroll
    for (int e = 0; e < 8; ++e) if (e != i1 && p[e] > p2) { p2 = p[e]; i2 = e; }
    float w1 = p1 / (p1 + p2);
    if (lane == 0) {
      topi[t] = i1 | (i2 << 8);
      topw[t] = w1;
      #pragma unroll
      for (int e = 0; e < 8; ++e) pacc[e] += p[e] * inv;
      cacc[i1]++; cacc[i2]++;
    }
  }
  if (lane == 0) {
    #pragma unroll
    for (int e = 0; e < 8; ++e) { sP[wv][e] = pacc[e]; sC[wv][e] = cacc[e]; }
  }
  __syncthreads();
  if (tid < 8) {
    float ps = sP[0][tid] + sP[1][tid] + sP[2][tid] + sP[3][tid];
    int   cs = sC[0][tid] + sC[1][tid] + sC[2][tid] + sC[3][tid];
    atomicAdd(&cnt[tid], cs);
    atomicAdd(&psum[tid], (unsigned long long)((double)ps * 1099511627776.0));
  }
}

// ---------------- scan + aux ----------------
__global__ void scan_aux_kernel(int* __restrict__ stats,
                                const unsigned long long* __restrict__ psum,
                                float* __restrict__ aux_out)
{
  if (threadIdx.x == 0 && blockIdx.x == 0) {
    int b = 0, tb = 0;
    for (int e = 0; e < 8; ++e) {
      stats[8 + e] = b; stats[16 + e] = b; stats[24 + e] = tb;
      tb += (stats[e] + 127) >> 7;
      b += stats[e];
    }
    stats[32] = tb;
    double s = 0.0;
    for (int e = 0; e < 8; ++e)
      s += (double)stats[e] * ((double)psum[e] * (1.0 / 1099511627776.0));
    aux_out[0] = (float)(4.0 * s / ((double)N_TOK * (double)N_TOK));
  }
}

// ---------------- placement ----------------
__global__ __launch_bounds__(256) void place_kernel(
    const int* __restrict__ topi, const float* __restrict__ topw,
    int* __restrict__ stats, int* __restrict__ lpk, float* __restrict__ lw)
{
  int t = blockIdx.x * 256 + threadIdx.x;
  if (t >= N_TOK) return;
  int pk = topi[t];
  int e1 = pk & 0xff, e2 = (pk >> 8) & 0xff;
  float w1 = topw[t];
  int p1 = atomicAdd(&stats[8 + e1], 1);
  lpk[p1] = (t << 1); lw[p1] = w1;
  int p2 = atomicAdd(&stats[8 + e2], 1);
  lpk[p2] = (t << 1) | 1; lw[p2] = 1.f - w1;
}

// ---------------- gather tokens into chunk-image layout ----------------
__global__ __launch_bounds__(256) void gather_x_kernel(
    const float* __restrict__ x, const int* __restrict__ lpk,
    const int* __restrict__ stats, char* __restrict__ xgp)
{
  int b = blockIdx.x;
  if (b >= stats[32]) return;
  int e = 0;
  #pragma unroll
  for (int k = 1; k < 8; ++k) if (b >= stats[24 + k]) e = k;
  int tloc = b - stats[24 + e];
  int abase = stats[16 + e], Me = stats[e];
  int lane = threadIdx.x & 63, wv = threadIdx.x >> 6;
  char* base = xgp + (size_t)b * 64 * 8192;
  #pragma unroll 1
  for (int r = wv; r < 128; r += 4) {
    int lrow = tloc * 128 + r;
    bool valid = lrow < Me;
    const float* src = x + (valid ? (size_t)(lpk[abase + lrow] >> 1) * DIM : 0);
    int q = r >> 1;
    #pragma unroll
    for (int it = 0; it < 4; ++it) {
      int c16 = it * 64 + lane;
      int j = c16 >> 2, s = c16 & 3;
      ushort u8[8];
      if (valid) {
        float4 v0 = *(const float4*)(src + c16 * 8);
        float4 v1 = *(const float4*)(src + c16 * 8 + 4);
        u8[0] = f2bf(v0.x); u8[1] = f2bf(v0.y); u8[2] = f2bf(v0.z); u8[3] = f2bf(v0.w);
        u8[4] = f2bf(v1.x); u8[5] = f2bf(v1.y); u8[6] = f2bf(v1.z); u8[7] = f2bf(v1.w);
      } else {
        #pragma unroll
        for (int i = 0; i < 8; ++i) u8[i] = 0;
      }
      int p = (((r & 1) << 2) | s) ^ (q & 7);
      char* d = base + (size_t)j * 8192 + q * 128 + p * 16;
      *(ushort4*)d = *(ushort4*)&u8[0];
      *(ushort4*)(d + 8) = *(ushort4*)&u8[4];
    }
  }
}

// ---------------- pack wg+wu -> images (rows: 0-63 gate, 64-127 up) ----------------
__global__ __launch_bounds__(256) void pack_gu_kernel(
    const float* __restrict__ wg, const float* __restrict__ wu, char* __restrict__ p1)
{
  int j = blockIdx.x, tn = blockIdx.y, e = blockIdx.z;
  __shared__ float tg[32][65];
  __shared__ float tu[32][65];
  int t = threadIdx.x;
  const float* gs = wg + ((size_t)e * DIM + j * 32) * FFN + tn * 64;
  const float* us = wu + ((size_t)e * DIM + j * 32) * FFN + tn * 64;
  #pragma unroll
  for (int k2 = 0; k2 < 2; ++k2) {
    int idx = t + k2 * 256;
    int kk = idx >> 4, fq = idx & 15;
    *(float4*)&tg[kk][fq * 4] = *(const float4*)(gs + (size_t)kk * FFN + fq * 4);
    *(float4*)&tu[kk][fq * 4] = *(const float4*)(us + (size_t)kk * FFN + fq * 4);
  }
  __syncthreads();
  char* dst = p1 + ((size_t)((e * 22 + tn) * 64 + j)) * 8192;
  #pragma unroll
  for (int k2 = 0; k2 < 2; ++k2) {
    int L = t + k2 * 256;
    int q = L >> 3, v = (L & 7) ^ (q & 7);
    int r = 2 * q + (v >> 2), s = v & 3;
    const float* col = (r < 64) ? &tg[s * 8][r] : &tu[s * 8][r - 64];
    ushort u8[8];
    #pragma unroll
    for (int i = 0; i < 8; ++i) u8[i] = f2bf(col[i * 65]);
    *(ushort4*)(dst + (size_t)L * 16) = *(ushort4*)&u8[0];
    *(ushort4*)(dst + (size_t)L * 16 + 8) = *(ushort4*)&u8[4];
  }
}

// ---------------- pack wd -> images (rows = 128 d-cols) ----------------
__global__ __launch_bounds__(256) void pack_d_kernel(
    const float* __restrict__ wd, char* __restrict__ p2)
{
  int j = blockIdx.x, tn = blockIdx.y, e = blockIdx.z;
  __shared__ float t2[32][129];
  int t = threadIdx.x;
  const float* src = wd + ((size_t)e * FFN + j * 32) * DIM + tn * 128;
  #pragma unroll
  for (int k2 = 0; k2 < 4; ++k2) {
    int idx = t + k2 * 256;
    int kk = idx >> 5, dq = idx & 31;
    *(float4*)&t2[kk][dq * 4] = *(const float4*)(src + (size_t)kk * DIM + dq * 4);
  }
  __syncthreads();
  char* dst = p2 + ((size_t)((e * 16 + tn) * 44 + j)) * 8192;
  #pragma unroll
  for (int k2 = 0; k2 < 2; ++k2) {
    int L = t + k2 * 256;
    int q = L >> 3, v = (L & 7) ^ (q & 7);
    int r = 2 * q + (v >> 2), s = v & 3;
    ushort u8[8];
    #pragma unroll
    for (int i = 0; i < 8; ++i) u8[i] = f2bf(t2[s * 8 + i][r]);
    *(ushort4*)(dst + (size_t)L * 16) = *(ushort4*)&u8[0];
    *(ushort4*)(dst + (size_t)L * 16 + 8) = *(ushort4*)&u8[4];
  }
}

// =====================================================================
// GEMM core: 128x128 tile, BK=32, 4 waves (2Mx2N), 32KB LDS dbuf,
// depth-1 prefetch, counted vmcnt(4), 2 barriers/chunk, ~4 blocks/CU.
// All staging is contiguous 1KB/instruction from pre-packed images.
// =====================================================================

#define GSTAGE(AC, BC_, BUF) do { int d_ = (BUF) * 16384 + wv * 2048; \
  gload16((AC) + wv * 2048 + lane * 16, sm + d_); \
  gload16((AC) + wv * 2048 + 1024 + lane * 16, sm + d_ + 1024); \
  gload16((BC_) + wv * 2048 + lane * 16, sm + d_ + 8192); \
  gload16((BC_) + wv * 2048 + 1024 + lane * 16, sm + d_ + 8192 + 1024); \
} while (0)

#define KLOOP(NCH) \
  GSTAGE(aP, bP, 0); \
  _Pragma("unroll 1") \
  for (int j = 0; j < (NCH); ++j) { \
    if (j + 1 < (NCH)) { \
      GSTAGE(aP + (size_t)(j + 1) * 8192, bP + (size_t)(j + 1) * 8192, (j + 1) & 1); \
      asm volatile("s_waitcnt vmcnt(4)" ::: "memory"); \
    } else { \
      asm volatile("s_waitcnt vmcnt(0)" ::: "memory"); \
    } \
    BAR(); \
    int sb = (j & 1) * 16384; \
    int4v va[4], vb[4]; \
    _Pragma("unroll") for (int n = 0; n < 4; ++n) vb[n] = dsread(sb + adB[n]); \
    _Pragma("unroll") for (int m = 0; m < 4; ++m) va[m] = dsread(sb + adA[m]); \
    WAITL(); \
    __builtin_amdgcn_s_setprio(1); \
    _Pragma("unroll") for (int m = 0; m < 4; ++m) \
      _Pragma("unroll") for (int n = 0; n < 4; ++n) \
        acc[m][n] = MFMA16(BC(va[m]), BC(vb[n]), acc[m][n]); \
    __builtin_amdgcn_s_setprio(0); \
    BAR(); \
  }

// GEMM1: A = token tile image, B = {gate,up} image; h written to gemm2 image.
__global__ __launch_bounds__(256, 4) void gemm_gu_kernel(
    const char* __restrict__ xgp, const char* __restrict__ p1,
    const int* __restrict__ stats, char* __restrict__ hp)
{
  int e = blockIdx.z, Me = stats[e], tm = blockIdx.x;
  if (tm * 128 >= Me) return;
  int tn = blockIdx.y, tb = stats[24 + e];

  __shared__ char sm[32768];
  int tid = threadIdx.x, lane = tid & 63, wv = tid >> 6;
  const char* aP = xgp + (size_t)(tb + tm) * 64 * 8192;
  const char* bP = p1 + (size_t)((e * 22 + tn) * 64) * 8192;

  int wm = wv >> 1, wn = wv & 1, s = lane >> 4;
  int adA[4], adB[4];
  #pragma unroll
  for (int m = 0; m < 4; ++m) adA[m] = swz(wm * 64 + m * 16 + (lane & 15), s);
  #pragma unroll
  for (int n = 0; n < 4; ++n) adB[n] = 8192 + swz(wn * 64 + n * 16 + (lane & 15), s);

  f32x4 acc[4][4];
  #pragma unroll
  for (int m = 0; m < 4; ++m)
    #pragma unroll
    for (int n = 0; n < 4; ++n) acc[m][n] = (f32x4){0, 0, 0, 0};

  KLOOP(64);

  // epilogue: wn==1 holds up-proj; exchange via LDS, wn==0 applies SiLU*u.
  float* u_lds = (float*)sm;          // [128][64] f32 = 32KB
  if (wn == 1) {
    #pragma unroll
    for (int m = 0; m < 4; ++m)
      #pragma unroll
      for (int n = 0; n < 4; ++n)
        #pragma unroll
        for (int r = 0; r < 4; ++r) {
          int row = wm * 64 + m * 16 + (lane >> 4) * 4 + r;
          int c = n * 16 + (lane & 15);
          u_lds[row * 64 + c] = acc[m][n][r];
        }
  }
  __syncthreads();
  if (wn == 0) {
    char* hb = hp + (size_t)(tb + tm) * 44 * 8192;
    #pragma unroll
    for (int m = 0; m < 4; ++m)
      #pragma unroll
      for (int n = 0; n < 4; ++n)
        #pragma unroll
        for (int r = 0; r < 4; ++r) {
          int row = wm * 64 + m * 16 + (lane >> 4) * 4 + r;
          int c = n * 16 + (lane & 15);
          float g = acc[m][n][r];
          float u = u_lds[row * 64 + c];
          float hv = g * u / (1.f + __expf(-g));
          int f = tn * 64 + c;
          int j2 = f >> 5, s2 = (f >> 3) & 3, i2 = f & 7;
          int q = row >> 1;
          int p = (((row & 1) << 2) | s2) ^ (q & 7);
          *(ushort*)(hb + (size_t)j2 * 8192 + q * 128 + p * 16 + i2 * 2) = f2bf(hv);
        }
  }
}

// GEMM2: A = h image, B = down image; scatter-add into out with gate weight.
__global__ __launch_bounds__(256, 4) void gemm_down_kernel(
    const char* __restrict__ hp, const char* __restrict__ p2,
    const int* __restrict__ lpk, const float* __restrict__ lw,
    const int* __restrict__ stats, float* __restrict__ out)
{
  int e = blockIdx.z, Me = stats[e], tm = blockIdx.x;
  if (tm * 128 >= Me) return;
  int tn = blockIdx.y, tb = stats[24 + e], abase = stats[16 + e];

  __shared__ char sm[32768];
  int tid = threadIdx.x, lane = tid & 63, wv = tid >> 6;
  const char* aP = hp + (size_t)(tb + tm) * 44 * 8192;
  const char* bP = p2 + (size_t)((e * 16 + tn) * 44) * 8192;

  int wm = wv >> 1, wn = wv & 1, s = lane >> 4;
  int adA[4], adB[4];
  #pragma unroll
  for (int m = 0; m < 4; ++m) adA[m] = swz(wm * 64 + m * 16 + (lane & 15), s);
  #pragma unroll
  for (int n = 0; n < 4; ++n) adB[n] = 8192 + swz(wn * 64 + n * 16 + (lane & 15), s);

  f32x4 acc[4][4];
  #pragma unroll
  for (int m = 0; m < 4; ++m)
    #pragma unroll
    for (int n = 0; n < 4; ++n) acc[m][n] = (f32x4){0, 0, 0, 0};

  KLOOP(44);

  int c0 = lane & 15, r0 = (lane >> 4) * 4;
  #pragma unroll
  for (int m = 0; m < 4; ++m) {
    #pragma unroll
    for (int r = 0; r < 4; ++r) {
      int lrow = tm * 128 + wm * 64 + m * 16 + r0 + r;
      if (lrow < Me) {
        int t = lpk[abase + lrow] >> 1;
        float w = lw[abase + lrow];
        #pragma unroll
        for (int n = 0; n < 4; ++n) {
          int col = tn * 128 + wn * 64 + n * 16 + c0;
          unsafeAtomicAdd(&out[(size_t)t * DIM + col], w * acc[m][n][r]);
        }
      }
    }
  }
}

extern "C" void kernel_launch(void* const* d_in, const int* in_sizes, int n_in,
                              void* d_out, int out_size, void* d_ws, size_t ws_size,
                              hipStream_t stream)
{
  const float* x  = (const float*)d_in[0];
  const float* rw = (const float*)d_in[1];
  const float* wg = (const float*)d_in[2];
  const float* wu = (const float*)d_in[3];
  const float* wd = (const float*)d_in[4];
  float* out = (float*)d_out;

  char* ws = (char*)d_ws;
  char*   xgp  = ws + XGP_OFF;
  char*   p1   = ws + P1_OFF;
  char*   p2   = ws + P2_OFF;
  char*   hp   = ws + HP_OFF;
  int*    lpk  = (int*)(ws + LPK_OFF);
  float*  lw   = (float*)(ws + LW_OFF);
  int*    topi = (int*)(ws + TI_OFF);
  float*  topw = (float*)(ws + TW_OFF);
  int*    stats = (int*)(ws + ST_OFF);
  unsigned long long* psum = (unsigned long long*)(ws + ST_OFF + 192);

  hipMemsetAsync(d_out, 0, (size_t)out_size * sizeof(float), stream);
  hipMemsetAsync(ws + ST_OFF, 0, 256, stream);

  router_kernel<<<512, 256, 0, stream>>>(x, rw, topi, topw, stats, psum);
  scan_aux_kernel<<<1, 64, 0, stream>>>(stats, psum, out + (size_t)out_size - 1);
  place_kernel<<<32, 256, 0, stream>>>(topi, topw, stats, lpk, lw);

  gather_x_kernel<<<136, 256, 0, stream>>>(x, lpk, stats, xgp);
  pack_gu_kernel<<<dim3(64, 22, 8), 256, 0, stream>>>(wg, wu, p1);
  pack_d_kernel<<<dim3(44, 16, 8), 256, 0, stream>>>(wd, p2);

  gemm_gu_kernel<<<dim3(32, 22, 8), 256, 0, stream>>>(xgp, p1, stats, hp);
  gemm_down_kernel<<<dim3(32, 16, 8), 256, 0, stream>>>(hp, p2, lpk, lw, stats, out);
}

// Round 7
// 624.638 us; speedup vs baseline: 2.1070x; 1.2972x over previous
//
#include <hip/hip_runtime.h>

#define N_TOK 8192
#define DIM   2048
#define FFN   1408

// ---------- ws layout (bytes) ----------
#define XGP_OFF 0ull                  // packed x images: 136 tiles x 64 j x 8192
#define P1_OFF  71303168ull           // packed gate+up: 8 x 22 x 64 x 8192
#define P2_OFF  163577856ull          // packed down:    8 x 16 x 44 x 8192
#define HP_OFF  209715200ull          // packed h images: 136 x 44 x 8192
#define LPK_OFF 258736128ull          // [16384] int
#define LW_OFF  258801664ull          // [16384] f32
#define TI_OFF  258867200ull          // [8192] int
#define TW_OFF  258899968ull          // [8192] f32
#define ST_OFF  258932736ull          // ints: cnt8 cur8 abase8 tbase8 ttot ; psum u64[8] @+192

typedef __bf16 bf16x8 __attribute__((ext_vector_type(8)));
typedef float  f32x4  __attribute__((ext_vector_type(4)));
typedef int    int4v  __attribute__((ext_vector_type(4)));
typedef __attribute__((address_space(1))) void as1_void;
typedef __attribute__((address_space(3))) void as3_void;

__device__ __forceinline__ void gload16(const void* g, void* l) {
  __builtin_amdgcn_global_load_lds((as1_void*)g, (as3_void*)l, 16, 0, 0);
}

__device__ __forceinline__ ushort f2bf(float f) {
  unsigned u = __builtin_bit_cast(unsigned, f);
  u += 0x7FFFu + ((u >> 16) & 1u);
  return (ushort)(u >> 16);
}

__device__ __forceinline__ int4v dsread(int addr) {
  int4v d;
  asm volatile("ds_read_b128 %0, %1" : "=v"(d) : "v"(addr));
  return d;
}

#define WAITL() do { asm volatile("s_waitcnt lgkmcnt(0)" ::: "memory"); \
                     __builtin_amdgcn_sched_barrier(0); } while (0)
#define BAR()   __builtin_amdgcn_s_barrier()
#define MFMA16(a, b, c) __builtin_amdgcn_mfma_f32_16x16x32_bf16(a, b, c, 0, 0, 0)
#define BC(x) __builtin_bit_cast(bf16x8, x)

// 8KB unit = 128 rows x 32 k bf16. 16B piece (row, s): q=row>>1,
// p = (((row&1)<<2)|s) ^ (q&7); byte = q*128 + p*16.
__device__ __forceinline__ int swz(int row, int s) {
  int q = row >> 1;
  int p = (((row & 1) << 2) | s) ^ (q & 7);
  return q * 128 + p * 16;
}

// ---------------- router ----------------
__global__ __launch_bounds__(256) void router_kernel(
    const float* __restrict__ x, const float* __restrict__ rw,
    int* __restrict__ topi, float* __restrict__ topw,
    int* __restrict__ cnt, unsigned long long* __restrict__ psum)
{
  int tid = threadIdx.x, lane = tid & 63, wv = tid >> 6;
  __shared__ float sP[4][8];
  __shared__ int   sC[4][8];
  float pacc[8]; int cacc[8];
  #pragma unroll
  for (int e = 0; e < 8; ++e) { pacc[e] = 0.f; cacc[e] = 0; }

  #pragma unroll 1
  for (int it = 0; it < 4; ++it) {
    int t = blockIdx.x * 16 + wv * 4 + it;
    const float4* xr = (const float4*)(x + (size_t)t * DIM);
    float acc[8];
    #pragma unroll
    for (int e = 0; e < 8; ++e) acc[e] = 0.f;
    #pragma unroll 1
    for (int i = 0; i < 8; ++i) {
      int j = i * 64 + lane;
      float4 v = xr[j];
      const float* rr = rw + (size_t)j * 32;
      #pragma unroll
      for (int c = 0; c < 4; ++c) {
        float xv = (&v.x)[c];
        const float4* r4 = (const float4*)(rr + c * 8);
        float4 q0 = r4[0], q1 = r4[1];
        acc[0] += xv * q0.x; acc[1] += xv * q0.y; acc[2] += xv * q0.z; acc[3] += xv * q0.w;
        acc[4] += xv * q1.x; acc[5] += xv * q1.y; acc[6] += xv * q1.z; acc[7] += xv * q1.w;
      }
    }
    #pragma unroll
    for (int off = 32; off; off >>= 1) {
      #pragma unroll
      for (int e = 0; e < 8; ++e) acc[e] += __shfl_xor(acc[e], off);
    }
    float m = acc[0];
    #pragma unroll
    for (int e = 1; e < 8; ++e) m = fmaxf(m, acc[e]);
    float p[8], s = 0.f;
    #pragma unroll
    for (int e = 0; e < 8; ++e) { p[e] = __expf(acc[e] - m); s += p[e]; }
    float inv = 1.f / s;
    int i1 = 0; float p1 = p[0];
    #pragma unroll
    for (int e = 1; e < 8; ++e) if (p[e] > p1) { p1 = p[e]; i1 = e; }
    int i2 = -1; float p2 = -1.f;
    #pragma unroll
    for (int e = 0; e < 8; ++e) if (e != i1 && p[e] > p2) { p2 = p[e]; i2 = e; }
    float w1 = p1 / (p1 + p2);
    if (lane == 0) {
      topi[t] = i1 | (i2 << 8);
      topw[t] = w1;
      #pragma unroll
      for (int e = 0; e < 8; ++e) pacc[e] += p[e] * inv;
      cacc[i1]++; cacc[i2]++;
    }
  }
  if (lane == 0) {
    #pragma unroll
    for (int e = 0; e < 8; ++e) { sP[wv][e] = pacc[e]; sC[wv][e] = cacc[e]; }
  }
  __syncthreads();
  if (tid < 8) {
    float ps = sP[0][tid] + sP[1][tid] + sP[2][tid] + sP[3][tid];
    int   cs = sC[0][tid] + sC[1][tid] + sC[2][tid] + sC[3][tid];
    atomicAdd(&cnt[tid], cs);
    atomicAdd(&psum[tid], (unsigned long long)((double)ps * 1099511627776.0));
  }
}

// ---------------- scan + aux ----------------
__global__ void scan_aux_kernel(int* __restrict__ stats,
                                const unsigned long long* __restrict__ psum,
                                float* __restrict__ aux_out)
{
  if (threadIdx.x == 0 && blockIdx.x == 0) {
    int b = 0, tb = 0;
    for (int e = 0; e < 8; ++e) {
      stats[8 + e] = b; stats[16 + e] = b; stats[24 + e] = tb;
      tb += (stats[e] + 127) >> 7;
      b += stats[e];
    }
    stats[32] = tb;
    double s = 0.0;
    for (int e = 0; e < 8; ++e)
      s += (double)stats[e] * ((double)psum[e] * (1.0 / 1099511627776.0));
    aux_out[0] = (float)(4.0 * s / ((double)N_TOK * (double)N_TOK));
  }
}

// ---------------- placement ----------------
__global__ __launch_bounds__(256) void place_kernel(
    const int* __restrict__ topi, const float* __restrict__ topw,
    int* __restrict__ stats, int* __restrict__ lpk, float* __restrict__ lw)
{
  int t = blockIdx.x * 256 + threadIdx.x;
  if (t >= N_TOK) return;
  int pk = topi[t];
  int e1 = pk & 0xff, e2 = (pk >> 8) & 0xff;
  float w1 = topw[t];
  int p1 = atomicAdd(&stats[8 + e1], 1);
  lpk[p1] = (t << 1); lw[p1] = w1;
  int p2 = atomicAdd(&stats[8 + e2], 1);
  lpk[p2] = (t << 1) | 1; lw[p2] = 1.f - w1;
}

// ---------------- gather tokens into chunk-image layout ----------------
__global__ __launch_bounds__(256) void gather_x_kernel(
    const float* __restrict__ x, const int* __restrict__ lpk,
    const int* __restrict__ stats, char* __restrict__ xgp)
{
  int b = blockIdx.x;
  if (b >= stats[32]) return;
  int e = 0;
  #pragma unroll
  for (int k = 1; k < 8; ++k) if (b >= stats[24 + k]) e = k;
  int tloc = b - stats[24 + e];
  int abase = stats[16 + e], Me = stats[e];
  int lane = threadIdx.x & 63, wv = threadIdx.x >> 6;
  char* base = xgp + (size_t)b * 64 * 8192;
  #pragma unroll 1
  for (int r = wv; r < 128; r += 4) {
    int lrow = tloc * 128 + r;
    bool valid = lrow < Me;
    const float* src = x + (valid ? (size_t)(lpk[abase + lrow] >> 1) * DIM : 0);
    int q = r >> 1;
    #pragma unroll
    for (int it = 0; it < 4; ++it) {
      int c16 = it * 64 + lane;
      int j = c16 >> 2, s = c16 & 3;
      ushort u8[8];
      if (valid) {
        float4 v0 = *(const float4*)(src + c16 * 8);
        float4 v1 = *(const float4*)(src + c16 * 8 + 4);
        u8[0] = f2bf(v0.x); u8[1] = f2bf(v0.y); u8[2] = f2bf(v0.z); u8[3] = f2bf(v0.w);
        u8[4] = f2bf(v1.x); u8[5] = f2bf(v1.y); u8[6] = f2bf(v1.z); u8[7] = f2bf(v1.w);
      } else {
        #pragma unroll
        for (int i = 0; i < 8; ++i) u8[i] = 0;
      }
      int p = (((r & 1) << 2) | s) ^ (q & 7);
      char* d = base + (size_t)j * 8192 + q * 128 + p * 16;
      *(ushort4*)d = *(ushort4*)&u8[0];
      *(ushort4*)(d + 8) = *(ushort4*)&u8[4];
    }
  }
}

// ---------------- pack wg+wu -> images (rows: 0-63 gate, 64-127 up) ----------------
__global__ __launch_bounds__(256) void pack_gu_kernel(
    const float* __restrict__ wg, const float* __restrict__ wu, char* __restrict__ p1)
{
  int j = blockIdx.x, tn = blockIdx.y, e = blockIdx.z;
  __shared__ float tg[32][65];
  __shared__ float tu[32][65];
  int t = threadIdx.x;
  const float* gs = wg + ((size_t)e * DIM + j * 32) * FFN + tn * 64;
  const float* us = wu + ((size_t)e * DIM + j * 32) * FFN + tn * 64;
  #pragma unroll
  for (int k2 = 0; k2 < 2; ++k2) {
    int idx = t + k2 * 256;
    int kk = idx >> 4, fq = idx & 15;
    *(float4*)&tg[kk][fq * 4] = *(const float4*)(gs + (size_t)kk * FFN + fq * 4);
    *(float4*)&tu[kk][fq * 4] = *(const float4*)(us + (size_t)kk * FFN + fq * 4);
  }
  __syncthreads();
  char* dst = p1 + ((size_t)((e * 22 + tn) * 64 + j)) * 8192;
  #pragma unroll
  for (int k2 = 0; k2 < 2; ++k2) {
    int L = t + k2 * 256;
    int q = L >> 3, v = (L & 7) ^ (q & 7);
    int r = 2 * q + (v >> 2), s = v & 3;
    const float* col = (r < 64) ? &tg[s * 8][r] : &tu[s * 8][r - 64];
    ushort u8[8];
    #pragma unroll
    for (int i = 0; i < 8; ++i) u8[i] = f2bf(col[i * 65]);
    *(ushort4*)(dst + (size_t)L * 16) = *(ushort4*)&u8[0];
    *(ushort4*)(dst + (size_t)L * 16 + 8) = *(ushort4*)&u8[4];
  }
}

// ---------------- pack wd -> images (rows = 128 d-cols) ----------------
__global__ __launch_bounds__(256) void pack_d_kernel(
    const float* __restrict__ wd, char* __restrict__ p2)
{
  int j = blockIdx.x, tn = blockIdx.y, e = blockIdx.z;
  __shared__ float t2[32][129];
  int t = threadIdx.x;
  const float* src = wd + ((size_t)e * FFN + j * 32) * DIM + tn * 128;
  #pragma unroll
  for (int k2 = 0; k2 < 4; ++k2) {
    int idx = t + k2 * 256;
    int kk = idx >> 5, dq = idx & 31;
    *(float4*)&t2[kk][dq * 4] = *(const float4*)(src + (size_t)kk * DIM + dq * 4);
  }
  __syncthreads();
  char* dst = p2 + ((size_t)((e * 16 + tn) * 44 + j)) * 8192;
  #pragma unroll
  for (int k2 = 0; k2 < 2; ++k2) {
    int L = t + k2 * 256;
    int q = L >> 3, v = (L & 7) ^ (q & 7);
    int r = 2 * q + (v >> 2), s = v & 3;
    ushort u8[8];
    #pragma unroll
    for (int i = 0; i < 8; ++i) u8[i] = f2bf(t2[s * 8 + i][r]);
    *(ushort4*)(dst + (size_t)L * 16) = *(ushort4*)&u8[0];
    *(ushort4*)(dst + (size_t)L * 16 + 8) = *(ushort4*)&u8[4];
  }
}

// =====================================================================
// GEMM core: 128x128 tile, BK=32, 4 waves (2Mx2N), 32KB LDS dbuf,
// depth-1 prefetch, counted vmcnt(4), ~4-5 blocks/CU.
// XCD-locality: bid&7 -> XCD -> expert; within XCD: tm outer, tn fast
// (A tile stays L2-resident across its tn sweep; concurrent tm-sweeps
// share B images through L2).
// =====================================================================

#define GSTAGE(AC, BC_, BUF) do { int d_ = (BUF) * 16384 + wv * 2048; \
  gload16((AC) + wv * 2048 + lane * 16, sm + d_); \
  gload16((AC) + wv * 2048 + 1024 + lane * 16, sm + d_ + 1024); \
  gload16((BC_) + wv * 2048 + lane * 16, sm + d_ + 8192); \
  gload16((BC_) + wv * 2048 + 1024 + lane * 16, sm + d_ + 8192 + 1024); \
} while (0)

#define KLOOP(NCH) \
  GSTAGE(aP, bP, 0); \
  _Pragma("unroll 1") \
  for (int j = 0; j < (NCH); ++j) { \
    if (j + 1 < (NCH)) { \
      GSTAGE(aP + (size_t)(j + 1) * 8192, bP + (size_t)(j + 1) * 8192, (j + 1) & 1); \
      asm volatile("s_waitcnt vmcnt(4)" ::: "memory"); \
    } else { \
      asm volatile("s_waitcnt vmcnt(0)" ::: "memory"); \
    } \
    BAR(); \
    int sb = (j & 1) * 16384; \
    int4v va[4], vb[4]; \
    _Pragma("unroll") for (int n = 0; n < 4; ++n) vb[n] = dsread(sb + adB[n]); \
    _Pragma("unroll") for (int m = 0; m < 4; ++m) va[m] = dsread(sb + adA[m]); \
    WAITL(); \
    __builtin_amdgcn_s_setprio(1); \
    _Pragma("unroll") for (int m = 0; m < 4; ++m) \
      _Pragma("unroll") for (int n = 0; n < 4; ++n) \
        acc[m][n] = MFMA16(BC(va[m]), BC(vb[n]), acc[m][n]); \
    __builtin_amdgcn_s_setprio(0); \
    BAR(); \
  }

// GEMM1: A = token tile image, B = {gate,up} image; h written to gemm2 image.
// grid: 5632 1D. e = bid&7 (XCD), local = bid>>3: tm = local/22, tn = local%22.
__global__ __launch_bounds__(256, 4) void gemm_gu_kernel(
    const char* __restrict__ xgp, const char* __restrict__ p1,
    const int* __restrict__ stats, char* __restrict__ hp)
{
  int bid = blockIdx.x;
  int e = bid & 7;
  int Ll = bid >> 3;
  int tm = Ll / 22, tn = Ll % 22;
  int Me = stats[e];
  if (tm * 128 >= Me) return;
  int tb = stats[24 + e];

  __shared__ char sm[32768];
  int tid = threadIdx.x, lane = tid & 63, wv = tid >> 6;
  const char* aP = xgp + (size_t)(tb + tm) * 64 * 8192;
  const char* bP = p1 + (size_t)((e * 22 + tn) * 64) * 8192;

  int wm = wv >> 1, wn = wv & 1, s = lane >> 4;
  int adA[4], adB[4];
  #pragma unroll
  for (int m = 0; m < 4; ++m) adA[m] = swz(wm * 64 + m * 16 + (lane & 15), s);
  #pragma unroll
  for (int n = 0; n < 4; ++n) adB[n] = 8192 + swz(wn * 64 + n * 16 + (lane & 15), s);

  f32x4 acc[4][4];
  #pragma unroll
  for (int m = 0; m < 4; ++m)
    #pragma unroll
    for (int n = 0; n < 4; ++n) acc[m][n] = (f32x4){0, 0, 0, 0};

  KLOOP(64);

  // epilogue: wn==1 holds up-proj; exchange via LDS, wn==0 applies SiLU*u.
  float* u_lds = (float*)sm;          // [128][64] f32 = 32KB
  if (wn == 1) {
    #pragma unroll
    for (int m = 0; m < 4; ++m)
      #pragma unroll
      for (int n = 0; n < 4; ++n)
        #pragma unroll
        for (int r = 0; r < 4; ++r) {
          int row = wm * 64 + m * 16 + (lane >> 4) * 4 + r;
          int c = n * 16 + (lane & 15);
          u_lds[row * 64 + c] = acc[m][n][r];
        }
  }
  __syncthreads();
  if (wn == 0) {
    char* hb = hp + (size_t)(tb + tm) * 44 * 8192;
    #pragma unroll
    for (int m = 0; m < 4; ++m)
      #pragma unroll
      for (int n = 0; n < 4; ++n)
        #pragma unroll
        for (int r = 0; r < 4; ++r) {
          int row = wm * 64 + m * 16 + (lane >> 4) * 4 + r;
          int c = n * 16 + (lane & 15);
          float g = acc[m][n][r];
          float u = u_lds[row * 64 + c];
          float hv = g * u / (1.f + __expf(-g));
          int f = tn * 64 + c;
          int j2 = f >> 5, s2 = (f >> 3) & 3, i2 = f & 7;
          int q = row >> 1;
          int p = (((row & 1) << 2) | s2) ^ (q & 7);
          *(ushort*)(hb + (size_t)j2 * 8192 + q * 128 + p * 16 + i2 * 2) = f2bf(hv);
        }
  }
}

// GEMM2: A = h image, B = down image; scatter-add into out with gate weight.
// grid: 4096 1D. e = bid&7, local = bid>>3: tm = local>>4, tn = local&15.
__global__ __launch_bounds__(256, 4) void gemm_down_kernel(
    const char* __restrict__ hp, const char* __restrict__ p2,
    const int* __restrict__ lpk, const float* __restrict__ lw,
    const int* __restrict__ stats, float* __restrict__ out)
{
  int bid = blockIdx.x;
  int e = bid & 7;
  int Ll = bid >> 3;
  int tm = Ll >> 4, tn = Ll & 15;
  int Me = stats[e];
  if (tm * 128 >= Me) return;
  int tb = stats[24 + e], abase = stats[16 + e];

  __shared__ char sm[32768];
  int tid = threadIdx.x, lane = tid & 63, wv = tid >> 6;
  const char* aP = hp + (size_t)(tb + tm) * 44 * 8192;
  const char* bP = p2 + (size_t)((e * 16 + tn) * 44) * 8192;

  int wm = wv >> 1, wn = wv & 1, s = lane >> 4;
  int adA[4], adB[4];
  #pragma unroll
  for (int m = 0; m < 4; ++m) adA[m] = swz(wm * 64 + m * 16 + (lane & 15), s);
  #pragma unroll
  for (int n = 0; n < 4; ++n) adB[n] = 8192 + swz(wn * 64 + n * 16 + (lane & 15), s);

  f32x4 acc[4][4];
  #pragma unroll
  for (int m = 0; m < 4; ++m)
    #pragma unroll
    for (int n = 0; n < 4; ++n) acc[m][n] = (f32x4){0, 0, 0, 0};

  KLOOP(44);

  int c0 = lane & 15, r0 = (lane >> 4) * 4;
  #pragma unroll
  for (int m = 0; m < 4; ++m) {
    #pragma unroll
    for (int r = 0; r < 4; ++r) {
      int lrow = tm * 128 + wm * 64 + m * 16 + r0 + r;
      if (lrow < Me) {
        int t = lpk[abase + lrow] >> 1;
        float w = lw[abase + lrow];
        #pragma unroll
        for (int n = 0; n < 4; ++n) {
          int col = tn * 128 + wn * 64 + n * 16 + c0;
          unsafeAtomicAdd(&out[(size_t)t * DIM + col], w * acc[m][n][r]);
        }
      }
    }
  }
}

extern "C" void kernel_launch(void* const* d_in, const int* in_sizes, int n_in,
                              void* d_out, int out_size, void* d_ws, size_t ws_size,
                              hipStream_t stream)
{
  const float* x  = (const float*)d_in[0];
  const float* rw = (const float*)d_in[1];
  const float* wg = (const float*)d_in[2];
  const float* wu = (const float*)d_in[3];
  const float* wd = (const float*)d_in[4];
  float* out = (float*)d_out;

  char* ws = (char*)d_ws;
  char*   xgp  = ws + XGP_OFF;
  char*   p1   = ws + P1_OFF;
  char*   p2   = ws + P2_OFF;
  char*   hp   = ws + HP_OFF;
  int*    lpk  = (int*)(ws + LPK_OFF);
  float*  lw   = (float*)(ws + LW_OFF);
  int*    topi = (int*)(ws + TI_OFF);
  float*  topw = (float*)(ws + TW_OFF);
  int*    stats = (int*)(ws + ST_OFF);
  unsigned long long* psum = (unsigned long long*)(ws + ST_OFF + 192);

  hipMemsetAsync(d_out, 0, (size_t)out_size * sizeof(float), stream);
  hipMemsetAsync(ws + ST_OFF, 0, 256, stream);

  router_kernel<<<512, 256, 0, stream>>>(x, rw, topi, topw, stats, psum);
  scan_aux_kernel<<<1, 64, 0, stream>>>(stats, psum, out + (size_t)out_size - 1);
  place_kernel<<<32, 256, 0, stream>>>(topi, topw, stats, lpk, lw);

  gather_x_kernel<<<136, 256, 0, stream>>>(x, lpk, stats, xgp);
  pack_gu_kernel<<<dim3(64, 22, 8), 256, 0, stream>>>(wg, wu, p1);
  pack_d_kernel<<<dim3(44, 16, 8), 256, 0, stream>>>(wd, p2);

  gemm_gu_kernel<<<5632, 256, 0, stream>>>(xgp, p1, stats, hp);
  gemm_down_kernel<<<4096, 256, 0, stream>>>(hp, p2, lpk, lw, stats, out);
}

// Round 8
// 581.945 us; speedup vs baseline: 2.2616x; 1.0734x over previous
//
#include <hip/hip_runtime.h>

#define N_TOK 8192
#define DIM   2048
#define FFN   1408

// ---------- ws layout (bytes); top = 258,932,992 (proven fit) ----------
// lifetimes:  xb: router->gather   hp: gemm_gu->gemm_down (aliases xb)
//             xgp: gather->gemm_gu p1: pack->gemm_gu
//             eo: gemm_down->combine (aliases xgp + p1 head, both dead)
#define XB_OFF  0ull                   // bf16 x [8192][2048] = 33,554,432
#define HP_OFF  0ull                   // h images 136x44x8192 = 49,020,928
#define XGP_OFF 49020928ull            // x images 136x64x8192 = 71,303,168
#define P1_OFF  120324096ull           // gate+up images 8x22x64x8192 = 92,274,688
#define EO_OFF  49020928ull            // eo f32 [16384][2048] = 134,217,728
#define P2_OFF  212598784ull           // down images 8x16x44x8192 = 46,137,344
#define LPK_OFF 258736128ull           // [16384] int
#define TI_OFF  258801664ull           // [8192] int
#define TW_OFF  258834432ull           // [8192] f32
#define TP_OFF  258867200ull           // [8192] int2
#define ST_OFF  258932736ull           // cnt8 cur8 abase8 tbase8 ttot ; psum u64[8] @+192

typedef __bf16 bf16x8 __attribute__((ext_vector_type(8)));
typedef float  f32x4  __attribute__((ext_vector_type(4)));
typedef int    int4v  __attribute__((ext_vector_type(4)));
typedef __attribute__((address_space(1))) void as1_void;
typedef __attribute__((address_space(3))) void as3_void;

__device__ __forceinline__ void gload16(const void* g, void* l) {
  __builtin_amdgcn_global_load_lds((as1_void*)g, (as3_void*)l, 16, 0, 0);
}

__device__ __forceinline__ ushort f2bf(float f) {
  unsigned u = __builtin_bit_cast(unsigned, f);
  u += 0x7FFFu + ((u >> 16) & 1u);
  return (ushort)(u >> 16);
}

__device__ __forceinline__ int4v dsread(int addr) {
  int4v d;
  asm volatile("ds_read_b128 %0, %1" : "=v"(d) : "v"(addr));
  return d;
}

#define WAITL() do { asm volatile("s_waitcnt lgkmcnt(0)" ::: "memory"); \
                     __builtin_amdgcn_sched_barrier(0); } while (0)
#define BAR()   __builtin_amdgcn_s_barrier()
#define MFMA16(a, b, c) __builtin_amdgcn_mfma_f32_16x16x32_bf16(a, b, c, 0, 0, 0)
#define BC(x) __builtin_bit_cast(bf16x8, x)

// 8KB unit = 128 rows x 32 k bf16. 16B piece (row, s): q=row>>1,
// p = (((row&1)<<2)|s) ^ (q&7); byte = q*128 + p*16.
__device__ __forceinline__ int swz(int row, int s) {
  int q = row >> 1;
  int p = (((row & 1) << 2) | s) ^ (q & 7);
  return q * 128 + p * 16;
}

// ---------------- router (+ x -> bf16) ----------------
__global__ __launch_bounds__(256) void router_kernel(
    const float* __restrict__ x, const float* __restrict__ rw,
    ushort* __restrict__ xb, int* __restrict__ topi, float* __restrict__ topw,
    int* __restrict__ cnt, unsigned long long* __restrict__ psum)
{
  int tid = threadIdx.x, lane = tid & 63, wv = tid >> 6;
  __shared__ float sP[4][8];
  __shared__ int   sC[4][8];
  float pacc[8]; int cacc[8];
  #pragma unroll
  for (int e = 0; e < 8; ++e) { pacc[e] = 0.f; cacc[e] = 0; }

  #pragma unroll 1
  for (int it = 0; it < 4; ++it) {
    int t = blockIdx.x * 16 + wv * 4 + it;
    const float4* xr = (const float4*)(x + (size_t)t * DIM);
    float acc[8];
    #pragma unroll
    for (int e = 0; e < 8; ++e) acc[e] = 0.f;
    #pragma unroll 1
    for (int i = 0; i < 8; ++i) {
      int j = i * 64 + lane;
      float4 v = xr[j];
      ushort4 o; o.x = f2bf(v.x); o.y = f2bf(v.y); o.z = f2bf(v.z); o.w = f2bf(v.w);
      *(ushort4*)(xb + (size_t)t * DIM + (size_t)j * 4) = o;
      const float* rr = rw + (size_t)j * 32;
      #pragma unroll
      for (int c = 0; c < 4; ++c) {
        float xv = (&v.x)[c];
        const float4* r4 = (const float4*)(rr + c * 8);
        float4 q0 = r4[0], q1 = r4[1];
        acc[0] += xv * q0.x; acc[1] += xv * q0.y; acc[2] += xv * q0.z; acc[3] += xv * q0.w;
        acc[4] += xv * q1.x; acc[5] += xv * q1.y; acc[6] += xv * q1.z; acc[7] += xv * q1.w;
      }
    }
    #pragma unroll
    for (int off = 32; off; off >>= 1) {
      #pragma unroll
      for (int e = 0; e < 8; ++e) acc[e] += __shfl_xor(acc[e], off);
    }
    float m = acc[0];
    #pragma unroll
    for (int e = 1; e < 8; ++e) m = fmaxf(m, acc[e]);
    float p[8], s = 0.f;
    #pragma unroll
    for (int e = 0; e < 8; ++e) { p[e] = __expf(acc[e] - m); s += p[e]; }
    float inv = 1.f / s;
    int i1 = 0; float p1 = p[0];
    #pragma unroll
    for (int e = 1; e < 8; ++e) if (p[e] > p1) { p1 = p[e]; i1 = e; }
    int i2 = -1; float p2 = -1.f;
    #pragma unroll
    for (int e = 0; e < 8; ++e) if (e != i1 && p[e] > p2) { p2 = p[e]; i2 = e; }
    float w1 = p1 / (p1 + p2);
    if (lane == 0) {
      topi[t] = i1 | (i2 << 8);
      topw[t] = w1;
      #pragma unroll
      for (int e = 0; e < 8; ++e) pacc[e] += p[e] * inv;
      cacc[i1]++; cacc[i2]++;
    }
  }
  if (lane == 0) {
    #pragma unroll
    for (int e = 0; e < 8; ++e) { sP[wv][e] = pacc[e]; sC[wv][e] = cacc[e]; }
  }
  __syncthreads();
  if (tid < 8) {
    float ps = sP[0][tid] + sP[1][tid] + sP[2][tid] + sP[3][tid];
    int   cs = sC[0][tid] + sC[1][tid] + sC[2][tid] + sC[3][tid];
    atomicAdd(&cnt[tid], cs);
    atomicAdd(&psum[tid], (unsigned long long)((double)ps * 1099511627776.0));
  }
}

// ---------------- scan + aux ----------------
__global__ void scan_aux_kernel(int* __restrict__ stats,
                                const unsigned long long* __restrict__ psum,
                                float* __restrict__ aux_out)
{
  if (threadIdx.x == 0 && blockIdx.x == 0) {
    int b = 0, tb = 0;
    for (int e = 0; e < 8; ++e) {
      stats[8 + e] = b; stats[16 + e] = b; stats[24 + e] = tb;
      tb += (stats[e] + 127) >> 7;
      b += stats[e];
    }
    stats[32] = tb;
    double s = 0.0;
    for (int e = 0; e < 8; ++e)
      s += (double)stats[e] * ((double)psum[e] * (1.0 / 1099511627776.0));
    aux_out[0] = (float)(4.0 * s / ((double)N_TOK * (double)N_TOK));
  }
}

// ---------------- placement ----------------
__global__ __launch_bounds__(256) void place_kernel(
    const int* __restrict__ topi, int* __restrict__ stats,
    int* __restrict__ lpk, int2* __restrict__ tpos)
{
  int t = blockIdx.x * 256 + threadIdx.x;
  if (t >= N_TOK) return;
  int pk = topi[t];
  int e1 = pk & 0xff, e2 = (pk >> 8) & 0xff;
  int p1 = atomicAdd(&stats[8 + e1], 1);
  lpk[p1] = t;
  int p2 = atomicAdd(&stats[8 + e2], 1);
  lpk[p2] = t;
  tpos[t] = make_int2(p1, p2);
}

// ---------------- gather bf16 tokens into chunk-image layout ----------------
__global__ __launch_bounds__(256) void gather_x_kernel(
    const ushort* __restrict__ xb, const int* __restrict__ lpk,
    const int* __restrict__ stats, char* __restrict__ xgp)
{
  int b = blockIdx.x;
  if (b >= stats[32]) return;
  int e = 0;
  #pragma unroll
  for (int k = 1; k < 8; ++k) if (b >= stats[24 + k]) e = k;
  int tloc = b - stats[24 + e];
  int abase = stats[16 + e], Me = stats[e];
  int lane = threadIdx.x & 63, wv = threadIdx.x >> 6;
  char* base = xgp + (size_t)b * 64 * 8192;
  #pragma unroll 1
  for (int r = wv; r < 128; r += 4) {
    int lrow = tloc * 128 + r;
    bool valid = lrow < Me;
    const char* src = (const char*)xb + (valid ? (size_t)lpk[abase + lrow] * (DIM * 2) : 0);
    int q = r >> 1;
    #pragma unroll
    for (int it = 0; it < 4; ++it) {
      int c16 = it * 64 + lane;
      int j = c16 >> 2, s = c16 & 3;
      uint4 v;
      if (valid) v = *(const uint4*)(src + c16 * 16);
      else       v = make_uint4(0, 0, 0, 0);
      int p = (((r & 1) << 2) | s) ^ (q & 7);
      *(uint4*)(base + (size_t)j * 8192 + q * 128 + p * 16) = v;
    }
  }
}

// ---------------- pack wg+wu -> images (rows: 0-63 gate, 64-127 up) ----------------
__global__ __launch_bounds__(256) void pack_gu_kernel(
    const float* __restrict__ wg, const float* __restrict__ wu, char* __restrict__ p1)
{
  int j = blockIdx.x, tn = blockIdx.y, e = blockIdx.z;
  __shared__ float tg[32][65];
  __shared__ float tu[32][65];
  int t = threadIdx.x;
  const float* gs = wg + ((size_t)e * DIM + j * 32) * FFN + tn * 64;
  const float* us = wu + ((size_t)e * DIM + j * 32) * FFN + tn * 64;
  #pragma unroll
  for (int k2 = 0; k2 < 2; ++k2) {
    int idx = t + k2 * 256;
    int kk = idx >> 4, fq = idx & 15;
    *(float4*)&tg[kk][fq * 4] = *(const float4*)(gs + (size_t)kk * FFN + fq * 4);
    *(float4*)&tu[kk][fq * 4] = *(const float4*)(us + (size_t)kk * FFN + fq * 4);
  }
  __syncthreads();
  char* dst = p1 + ((size_t)((e * 22 + tn) * 64 + j)) * 8192;
  #pragma unroll
  for (int k2 = 0; k2 < 2; ++k2) {
    int L = t + k2 * 256;
    int q = L >> 3, v = (L & 7) ^ (q & 7);
    int r = 2 * q + (v >> 2), s = v & 3;
    const float* col = (r < 64) ? &tg[s * 8][r] : &tu[s * 8][r - 64];
    ushort u8[8];
    #pragma unroll
    for (int i = 0; i < 8; ++i) u8[i] = f2bf(col[i * 65]);
    *(ushort4*)(dst + (size_t)L * 16) = *(ushort4*)&u8[0];
    *(ushort4*)(dst + (size_t)L * 16 + 8) = *(ushort4*)&u8[4];
  }
}

// ---------------- pack wd -> images (rows = 128 d-cols) ----------------
__global__ __launch_bounds__(256) void pack_d_kernel(
    const float* __restrict__ wd, char* __restrict__ p2)
{
  int j = blockIdx.x, tn = blockIdx.y, e = blockIdx.z;
  __shared__ float t2[32][129];
  int t = threadIdx.x;
  const float* src = wd + ((size_t)e * FFN + j * 32) * DIM + tn * 128;
  #pragma unroll
  for (int k2 = 0; k2 < 4; ++k2) {
    int idx = t + k2 * 256;
    int kk = idx >> 5, dq = idx & 31;
    *(float4*)&t2[kk][dq * 4] = *(const float4*)(src + (size_t)kk * DIM + dq * 4);
  }
  __syncthreads();
  char* dst = p2 + ((size_t)((e * 16 + tn) * 44 + j)) * 8192;
  #pragma unroll
  for (int k2 = 0; k2 < 2; ++k2) {
    int L = t + k2 * 256;
    int q = L >> 3, v = (L & 7) ^ (q & 7);
    int r = 2 * q + (v >> 2), s = v & 3;
    ushort u8[8];
    #pragma unroll
    for (int i = 0; i < 8; ++i) u8[i] = f2bf(t2[s * 8 + i][r]);
    *(ushort4*)(dst + (size_t)L * 16) = *(ushort4*)&u8[0];
    *(ushort4*)(dst + (size_t)L * 16 + 8) = *(ushort4*)&u8[4];
  }
}

// =====================================================================
// GEMM core: 128x128 tile, BK=32, 4 waves (2Mx2N), 32KB LDS dbuf,
// depth-1 prefetch, counted vmcnt(4), ~5 blocks/CU.
// XCD-locality: bid&7 -> XCD -> expert; within XCD: tm outer, tn fast.
// =====================================================================

#define GSTAGE(AC, BC_, BUF) do { int d_ = (BUF) * 16384 + wv * 2048; \
  gload16((AC) + wv * 2048 + lane * 16, sm + d_); \
  gload16((AC) + wv * 2048 + 1024 + lane * 16, sm + d_ + 1024); \
  gload16((BC_) + wv * 2048 + lane * 16, sm + d_ + 8192); \
  gload16((BC_) + wv * 2048 + 1024 + lane * 16, sm + d_ + 8192 + 1024); \
} while (0)

#define KLOOP(NCH) \
  GSTAGE(aP, bP, 0); \
  _Pragma("unroll 1") \
  for (int j = 0; j < (NCH); ++j) { \
    if (j + 1 < (NCH)) { \
      GSTAGE(aP + (size_t)(j + 1) * 8192, bP + (size_t)(j + 1) * 8192, (j + 1) & 1); \
      asm volatile("s_waitcnt vmcnt(4)" ::: "memory"); \
    } else { \
      asm volatile("s_waitcnt vmcnt(0)" ::: "memory"); \
    } \
    BAR(); \
    int sb = (j & 1) * 16384; \
    int4v va[4], vb[4]; \
    _Pragma("unroll") for (int n = 0; n < 4; ++n) vb[n] = dsread(sb + adB[n]); \
    _Pragma("unroll") for (int m = 0; m < 4; ++m) va[m] = dsread(sb + adA[m]); \
    WAITL(); \
    __builtin_amdgcn_s_setprio(1); \
    _Pragma("unroll") for (int m = 0; m < 4; ++m) \
      _Pragma("unroll") for (int n = 0; n < 4; ++n) \
        acc[m][n] = MFMA16(BC(va[m]), BC(vb[n]), acc[m][n]); \
    __builtin_amdgcn_s_setprio(0); \
    BAR(); \
  }

// GEMM1: A = token tile image, B = {gate,up} image; h written to gemm2 image.
__global__ __launch_bounds__(256, 4) void gemm_gu_kernel(
    const char* __restrict__ xgp, const char* __restrict__ p1,
    const int* __restrict__ stats, char* __restrict__ hp)
{
  int bid = blockIdx.x;
  int e = bid & 7;
  int Ll = bid >> 3;
  int tm = Ll / 22, tn = Ll % 22;
  int Me = stats[e];
  if (tm * 128 >= Me) return;
  int tb = stats[24 + e];

  __shared__ char sm[32768];
  int tid = threadIdx.x, lane = tid & 63, wv = tid >> 6;
  const char* aP = xgp + (size_t)(tb + tm) * 64 * 8192;
  const char* bP = p1 + (size_t)((e * 22 + tn) * 64) * 8192;

  int wm = wv >> 1, wn = wv & 1, s = lane >> 4;
  int adA[4], adB[4];
  #pragma unroll
  for (int m = 0; m < 4; ++m) adA[m] = swz(wm * 64 + m * 16 + (lane & 15), s);
  #pragma unroll
  for (int n = 0; n < 4; ++n) adB[n] = 8192 + swz(wn * 64 + n * 16 + (lane & 15), s);

  f32x4 acc[4][4];
  #pragma unroll
  for (int m = 0; m < 4; ++m)
    #pragma unroll
    for (int n = 0; n < 4; ++n) acc[m][n] = (f32x4){0, 0, 0, 0};

  KLOOP(64);

  // epilogue: wn==1 holds up-proj; exchange via LDS, wn==0 applies SiLU*u.
  float* u_lds = (float*)sm;          // [128][64] f32 = 32KB
  if (wn == 1) {
    #pragma unroll
    for (int m = 0; m < 4; ++m)
      #pragma unroll
      for (int n = 0; n < 4; ++n)
        #pragma unroll
        for (int r = 0; r < 4; ++r) {
          int row = wm * 64 + m * 16 + (lane >> 4) * 4 + r;
          int c = n * 16 + (lane & 15);
          u_lds[row * 64 + c] = acc[m][n][r];
        }
  }
  __syncthreads();
  if (wn == 0) {
    char* hb = hp + (size_t)(tb + tm) * 44 * 8192;
    #pragma unroll
    for (int m = 0; m < 4; ++m)
      #pragma unroll
      for (int n = 0; n < 4; ++n)
        #pragma unroll
        for (int r = 0; r < 4; ++r) {
          int row = wm * 64 + m * 16 + (lane >> 4) * 4 + r;
          int c = n * 16 + (lane & 15);
          float g = acc[m][n][r];
          float u = u_lds[row * 64 + c];
          float hv = g * u / (1.f + __expf(-g));
          int f = tn * 64 + c;
          int j2 = f >> 5, s2 = (f >> 3) & 3, i2 = f & 7;
          int q = row >> 1;
          int p = (((row & 1) << 2) | s2) ^ (q & 7);
          *(ushort*)(hb + (size_t)j2 * 8192 + q * 128 + p * 16 + i2 * 2) = f2bf(hv);
        }
  }
}

// GEMM2: A = h image, B = down image; dense store to eo (no atomics).
__global__ __launch_bounds__(256, 4) void gemm_down_kernel(
    const char* __restrict__ hp, const char* __restrict__ p2,
    const int* __restrict__ stats, float* __restrict__ eo)
{
  int bid = blockIdx.x;
  int e = bid & 7;
  int Ll = bid >> 3;
  int tm = Ll >> 4, tn = Ll & 15;
  int Me = stats[e];
  if (tm * 128 >= Me) return;
  int tb = stats[24 + e], abase = stats[16 + e];

  __shared__ char sm[32768];
  int tid = threadIdx.x, lane = tid & 63, wv = tid >> 6;
  const char* aP = hp + (size_t)(tb + tm) * 44 * 8192;
  const char* bP = p2 + (size_t)((e * 16 + tn) * 44) * 8192;

  int wm = wv >> 1, wn = wv & 1, s = lane >> 4;
  int adA[4], adB[4];
  #pragma unroll
  for (int m = 0; m < 4; ++m) adA[m] = swz(wm * 64 + m * 16 + (lane & 15), s);
  #pragma unroll
  for (int n = 0; n < 4; ++n) adB[n] = 8192 + swz(wn * 64 + n * 16 + (lane & 15), s);

  f32x4 acc[4][4];
  #pragma unroll
  for (int m = 0; m < 4; ++m)
    #pragma unroll
    for (int n = 0; n < 4; ++n) acc[m][n] = (f32x4){0, 0, 0, 0};

  KLOOP(44);

  int c0 = lane & 15, r0 = (lane >> 4) * 4;
  #pragma unroll
  for (int m = 0; m < 4; ++m) {
    #pragma unroll
    for (int r = 0; r < 4; ++r) {
      int lrow = tm * 128 + wm * 64 + m * 16 + r0 + r;
      if (lrow < Me) {
        float* dst = eo + (size_t)(abase + lrow) * DIM + tn * 128 + wn * 64 + c0;
        #pragma unroll
        for (int n = 0; n < 4; ++n) dst[n * 16] = acc[m][n][r];
      }
    }
  }
}

// ---------------- combine: out[t] = w1*eo[p1] + w2*eo[p2] ----------------
__global__ __launch_bounds__(256) void combine_kernel(
    const float* __restrict__ eo, const int2* __restrict__ tpos,
    const float* __restrict__ topw, float* __restrict__ out)
{
  int t = blockIdx.x;
  int2 tp = tpos[t];
  float w1 = topw[t], w2 = 1.f - w1;
  const float4* r1 = (const float4*)(eo + (size_t)tp.x * DIM);
  const float4* r2 = (const float4*)(eo + (size_t)tp.y * DIM);
  float4* o = (float4*)(out + (size_t)t * DIM);
  #pragma unroll
  for (int k = 0; k < 2; ++k) {
    int i = threadIdx.x + k * 256;
    float4 a = r1[i], b = r2[i];
    float4 c;
    c.x = w1 * a.x + w2 * b.x;
    c.y = w1 * a.y + w2 * b.y;
    c.z = w1 * a.z + w2 * b.z;
    c.w = w1 * a.w + w2 * b.w;
    o[i] = c;
  }
}

extern "C" void kernel_launch(void* const* d_in, const int* in_sizes, int n_in,
                              void* d_out, int out_size, void* d_ws, size_t ws_size,
                              hipStream_t stream)
{
  const float* x  = (const float*)d_in[0];
  const float* rw = (const float*)d_in[1];
  const float* wg = (const float*)d_in[2];
  const float* wu = (const float*)d_in[3];
  const float* wd = (const float*)d_in[4];
  float* out = (float*)d_out;

  char* ws = (char*)d_ws;
  ushort* xb   = (ushort*)(ws + XB_OFF);
  char*   hp   = ws + HP_OFF;
  char*   xgp  = ws + XGP_OFF;
  char*   p1   = ws + P1_OFF;
  float*  eo   = (float*)(ws + EO_OFF);
  char*   p2   = ws + P2_OFF;
  int*    lpk  = (int*)(ws + LPK_OFF);
  int*    topi = (int*)(ws + TI_OFF);
  float*  topw = (float*)(ws + TW_OFF);
  int2*   tpos = (int2*)(ws + TP_OFF);
  int*    stats = (int*)(ws + ST_OFF);
  unsigned long long* psum = (unsigned long long*)(ws + ST_OFF + 192);

  hipMemsetAsync(ws + ST_OFF, 0, 256, stream);

  router_kernel<<<512, 256, 0, stream>>>(x, rw, xb, topi, topw, stats, psum);
  scan_aux_kernel<<<1, 64, 0, stream>>>(stats, psum, out + (size_t)out_size - 1);
  place_kernel<<<32, 256, 0, stream>>>(topi, stats, lpk, tpos);

  gather_x_kernel<<<136, 256, 0, stream>>>(xb, lpk, stats, xgp);
  pack_gu_kernel<<<dim3(64, 22, 8), 256, 0, stream>>>(wg, wu, p1);
  pack_d_kernel<<<dim3(44, 16, 8), 256, 0, stream>>>(wd, p2);

  gemm_gu_kernel<<<5632, 256, 0, stream>>>(xgp, p1, stats, hp);
  gemm_down_kernel<<<4096, 256, 0, stream>>>(hp, p2, stats, eo);

  combine_kernel<<<8192, 256, 0, stream>>>(eo, tpos, topw, out);
}